// Round 1
// baseline (7393.776 us; speedup 1.0000x reference)
//
#include <hip/hip_runtime.h>
#include <cstddef>

// Model dims
#define Bb 8
#define Ss 4
#define Nn 2000
#define Tt 16
#define Ff 10
#define Ee 16
#define H1 16
#define H2 8
#define NHh 4
#define DKk 8
#define DMm 16000
#define Dd 128

// ---------------- embed: x = inputs @ emb_W + emb_b ----------------
__global__ __launch_bounds__(256) void embed_kernel(
    const float* __restrict__ in, const float* __restrict__ eW,
    const float* __restrict__ eb, float* __restrict__ x)
{
    int g = blockIdx.x * 256 + threadIdx.x;      // B*N*T*E = 4,096,000
    int e = g & 15;
    int row = g >> 4;                             // (b*N+n)*T + t
    const float* ip = in + (size_t)row * Ff;
    float a = eb[e];
    #pragma unroll
    for (int f = 0; f < Ff; ++f) a += ip[f] * eW[f * Ee + e];
    x[g] = a;
}

// ---------------- LSTM1: hidden 16, gates 64 (one wave per (b,n)) ----------------
__global__ __launch_bounds__(256) void lstm1_kernel(
    const float* __restrict__ x, const float* __restrict__ W1,
    const float* __restrict__ U1, const float* __restrict__ b1,
    float* __restrict__ h1)
{
    int tid = threadIdx.x;
    int lane = tid & 63, wid = tid >> 6;
    int p = blockIdx.x * 4 + wid;                 // (b*N+n), 16000 total
    float wcol[16], ucol[16];
    #pragma unroll
    for (int e = 0; e < 16; ++e) wcol[e] = W1[e * 64 + lane];
    #pragma unroll
    for (int k = 0; k < 16; ++k) ucol[k] = U1[k * 64 + lane];
    float bj = b1[lane];
    float hv = 0.f, cv = 0.f;
    const float* xp = x + (size_t)p * (Tt * Ee);
    float* hp = h1 + (size_t)p * (Tt * H1);
    for (int t = 0; t < Tt; ++t) {
        float xv = (lane < 16) ? xp[t * 16 + lane] : 0.f;
        float z = bj;
        #pragma unroll
        for (int e = 0; e < 16; ++e) z += __shfl(xv, e) * wcol[e];
        #pragma unroll
        for (int k = 0; k < 16; ++k) z += __shfl(hv, k) * ucol[k];
        float fz = __shfl(z, (lane + 16) & 63);
        float gz = __shfl(z, (lane + 32) & 63);
        float oz = __shfl(z, (lane + 48) & 63);
        if (lane < 16) {
            float ig = 1.f / (1.f + __expf(-z));
            float fg = 1.f / (1.f + __expf(-fz));
            float og = 1.f / (1.f + __expf(-oz));
            cv = fg * cv + ig * tanhf(gz);
            hv = og * tanhf(cv);
            hp[t * 16 + lane] = hv;
        }
    }
}

// ---------------- LSTM2: hidden 8, gates 32 (two stocks per wave) ----------------
__global__ __launch_bounds__(256) void lstm2_kernel(
    const float* __restrict__ o1, const float* __restrict__ W2,
    const float* __restrict__ U2, const float* __restrict__ b2,
    float* __restrict__ h2)
{
    int tid = threadIdx.x;
    int lane = tid & 63, wid = tid >> 6;
    int j = lane & 31, half = lane >> 5, base = half << 5;
    int p = blockIdx.x * 8 + wid * 2 + half;      // 16000 total
    float wcol[16], ucol[8];
    #pragma unroll
    for (int e = 0; e < 16; ++e) wcol[e] = W2[e * 32 + j];
    #pragma unroll
    for (int k = 0; k < 8; ++k) ucol[k] = U2[k * 32 + j];
    float bj = b2[j];
    float hv = 0.f, cv = 0.f;
    const float* op = o1 + (size_t)p * (Tt * H1);
    float* hp = h2 + (size_t)p * (Tt * H2);
    for (int t = 0; t < Tt; ++t) {
        float xv = (j < 16) ? op[t * 16 + j] : 0.f;
        float z = bj;
        #pragma unroll
        for (int e = 0; e < 16; ++e) z += __shfl(xv, base + e) * wcol[e];
        #pragma unroll
        for (int k = 0; k < 8; ++k) z += __shfl(hv, base + k) * ucol[k];
        float fz = __shfl(z, base + ((j + 8) & 31));
        float gz = __shfl(z, base + ((j + 16) & 31));
        float oz = __shfl(z, base + ((j + 24) & 31));
        if (j < 8) {
            float ig = 1.f / (1.f + __expf(-z));
            float fg = 1.f / (1.f + __expf(-fz));
            float og = 1.f / (1.f + __expf(-oz));
            cv = fg * cv + ig * tanhf(gz);
            hv = og * tanhf(cv);
            hp[t * 8 + j] = hv;
        }
    }
}

// ---------------- block reduce (sum of two values over 256 threads) ----------------
__device__ __forceinline__ void block_reduce2(float& a, float& b)
{
    #pragma unroll
    for (int off = 32; off; off >>= 1) {
        a += __shfl_xor(a, off);
        b += __shfl_xor(b, off);
    }
    __shared__ float r[8];
    int tid = threadIdx.x;
    if ((tid & 63) == 0) { r[tid >> 6] = a; r[4 + (tid >> 6)] = b; }
    __syncthreads();
    a = r[0] + r[1] + r[2] + r[3];
    b = r[4] + r[5] + r[6] + r[7];
}

// ---------------- LN1 over N*H1=32000 per (b,t) row ----------------
__global__ __launch_bounds__(256) void ln1_kernel(
    const float* __restrict__ h1, const float* __restrict__ g,
    const float* __restrict__ bta, float* __restrict__ o1)
{
    int b = blockIdx.x >> 4, t = blockIdx.x & 15;
    int tid = threadIdx.x;
    float sum = 0.f, sq = 0.f;
    for (int i = tid; i < Nn * H1; i += 256) {
        int n = i >> 4, j = i & 15;
        float v = h1[(((size_t)b * Nn + n) * Tt + t) * H1 + j];
        sum += v; sq += v * v;
    }
    block_reduce2(sum, sq);
    float mu = sum * (1.f / (Nn * H1));
    float var = sq * (1.f / (Nn * H1)) - mu * mu;
    float rstd = rsqrtf(var + 1e-5f);
    for (int i = tid; i < Nn * H1; i += 256) {
        int n = i >> 4, j = i & 15;
        size_t idx = (((size_t)b * Nn + n) * Tt + t) * H1 + j;
        o1[idx] = (h1[idx] - mu) * rstd * g[i] + bta[i];
    }
}

// ---------------- QKV projection: [128 rows, K=16000] -> 96 cols ----------------
__global__ __launch_bounds__(256) void qkv_kernel(
    const float* __restrict__ h2, const float* __restrict__ Wq,
    const float* __restrict__ Wk, const float* __restrict__ Wv,
    float* __restrict__ qb, float* __restrict__ kb, float* __restrict__ vb)
{
    int b = blockIdx.x >> 4, t = blockIdx.x & 15;
    int tid = threadIdx.x;
    __shared__ float lds[512];
    __shared__ float part[192];
    int out = tid % 96, sl = tid / 96;            // valid for tid<192
    const float* W = Wq; int c = out;
    if (out >= 64) { W = Wv; c = out - 64; }
    else if (out >= 32) { W = Wk; c = out - 32; }
    float acc = 0.f;
    for (int k0 = 0; k0 < DMm; k0 += 512) {
        __syncthreads();
        for (int i = tid; i < 512; i += 256) {
            int m = k0 + i;
            float v = 0.f;
            if (m < DMm) {
                int n = m >> 3, jj = m & 7;
                v = h2[(((size_t)b * Nn + n) * Tt + t) * H2 + jj];
            }
            lds[i] = v;
        }
        __syncthreads();
        if (tid < 192) {
            int kb0 = sl * 256;
            for (int kk = 0; kk < 256; ++kk) {
                int m2 = k0 + kb0 + kk;
                if (m2 < DMm) acc += lds[kb0 + kk] * W[(size_t)m2 * 32 + c];
            }
        }
    }
    if (tid < 192) part[tid] = acc;
    __syncthreads();
    if (tid < 96) {
        float v = part[tid] + part[tid + 96];
        int which = tid / 32, cc = tid % 32, h = cc >> 3, dk = cc & 7;
        float* dst = (which == 0) ? qb : ((which == 1) ? kb : vb);
        dst[(((size_t)b * NHh + h) * Tt + t) * DKk + dk] = v;
    }
}

// ---------------- causal attention per (b,h): T=16, DK=DV=8 ----------------
__global__ __launch_bounds__(256) void attn_kernel(
    const float* __restrict__ qb, const float* __restrict__ kb,
    const float* __restrict__ vb, float* __restrict__ ctx)
{
    int bh = blockIdx.x;                           // b*4 + h
    int b = bh >> 2, h = bh & 3;
    __shared__ float qs[128], ks[128], vs[128], att[16][16];
    int tid = threadIdx.x;
    if (tid < 128) {
        qs[tid] = qb[(size_t)bh * 128 + tid];
        ks[tid] = kb[(size_t)bh * 128 + tid];
        vs[tid] = vb[(size_t)bh * 128 + tid];
    }
    __syncthreads();
    int qt = tid >> 4, kt = tid & 15;
    float s = -1e9f;
    if (kt <= qt) {
        float d = 0.f;
        #pragma unroll
        for (int x = 0; x < 8; ++x) d += qs[qt * 8 + x] * ks[kt * 8 + x];
        s = d * 0.35355339059327373f;              // 1/sqrt(8)
    }
    float mx = s;
    #pragma unroll
    for (int off = 8; off; off >>= 1) mx = fmaxf(mx, __shfl_xor(mx, off, 16));
    float p = __expf(s - mx);
    float sm = p;
    #pragma unroll
    for (int off = 8; off; off >>= 1) sm += __shfl_xor(sm, off, 16);
    att[qt][kt] = p / sm;
    __syncthreads();
    if (tid < 128) {
        int q2 = tid >> 3, dv = tid & 7;
        float cacc = 0.f;
        #pragma unroll
        for (int k2 = 0; k2 < 16; ++k2) cacc += att[q2][k2] * vs[k2 * 8 + dv];
        ctx[((size_t)b * Tt + q2) * 32 + h * 8 + dv] = cacc;
    }
}

// ---------------- residual + out-proj + LN2, writes Xf in [N, B*D] layout ----------------
__global__ __launch_bounds__(256) void ln2_kernel(
    const float* __restrict__ h2, const float* __restrict__ ctx,
    const float* __restrict__ Wo, const float* __restrict__ g2,
    const float* __restrict__ b2v, float* __restrict__ resid,
    float* __restrict__ Xf)
{
    int b = blockIdx.x >> 4, t = blockIdx.x & 15;
    int tid = threadIdx.x;
    __shared__ float cs[32];
    if (tid < 32) cs[tid] = ctx[((size_t)b * Tt + t) * 32 + tid];
    __syncthreads();
    float sum = 0.f, sq = 0.f;
    for (int m = tid; m < DMm; m += 256) {
        int n = m >> 3, jj = m & 7;
        float v = h2[(((size_t)b * Nn + n) * Tt + t) * H2 + jj];
        #pragma unroll
        for (int j = 0; j < 32; ++j) v += cs[j] * Wo[(size_t)j * DMm + m];
        resid[((size_t)b * Tt + t) * DMm + m] = v;
        sum += v; sq += v * v;
    }
    block_reduce2(sum, sq);
    float mu = sum * (1.f / DMm);
    float var = sq * (1.f / DMm) - mu * mu;
    float rstd = rsqrtf(var + 1e-5f);
    for (int m = tid; m < DMm; m += 256) {
        float v = resid[((size_t)b * Tt + t) * DMm + m];
        float y = (v - mu) * rstd * g2[m] + b2v[m];
        int n = m >> 3, jj = m & 7;
        Xf[(size_t)n * 1024 + b * 128 + t * 8 + jj] = y;
    }
}

// ---------------- theta GEMM: Y[m, b*128+d] = sum_d0 X[m, b*128+d0]*theta[d0,d] ----------------
__global__ __launch_bounds__(128) void theta_kernel(
    const float* __restrict__ X, const float* __restrict__ theta,
    float* __restrict__ Y)
{
    int m = blockIdx.x, b = blockIdx.y;
    __shared__ float row[128];
    int tid = threadIdx.x;
    size_t off = (size_t)m * 1024 + (size_t)b * 128;
    row[tid] = X[off + tid];
    __syncthreads();
    float acc = 0.f;
    #pragma unroll 8
    for (int d0 = 0; d0 < 128; ++d0) acc += row[d0] * theta[d0 * 128 + tid];
    Y[off + tid] = acc;
}

// ---------------- main fp32 GEMM: C[M x 1024] = A[M x K] @ (B .* rowscale) ----------------
// mode 0: C = AB ; 1: C = leaky(AB) ; 2: C = par*leaky(AB) ; 3: C += par*leaky(AB)
__global__ __launch_bounds__(256) void hgemm_f32(
    const float* __restrict__ A, const float* __restrict__ Bm,
    float* __restrict__ C, const float* __restrict__ rowscale,
    const float* __restrict__ par, int sidx, int mode, int M, int K)
{
    const int NN = 1024;
    __shared__ float As[32][68];
    __shared__ float Bs[32][68];
    const int tid = threadIdx.x;
    const int m0 = blockIdx.x * 64, n0 = blockIdx.y * 64;
    const int ty = tid >> 4, tx = tid & 15;
    float acc[4][4] = {};
    const int ntiles = (K + 31) >> 5;
    for (int kt = 0; kt < ntiles; ++kt) {
        const int k0 = kt << 5;
        #pragma unroll
        for (int p = 0; p < 2; ++p) {
            int li = tid + p * 256;
            int row = li >> 3, c4 = (li & 7) << 2;
            int gm = m0 + row, gk = k0 + c4;
            float4 av = make_float4(0.f, 0.f, 0.f, 0.f);
            if (gm < M && gk < K)
                av = *(const float4*)(A + (size_t)gm * K + gk);
            As[c4 + 0][row] = av.x; As[c4 + 1][row] = av.y;
            As[c4 + 2][row] = av.z; As[c4 + 3][row] = av.w;
        }
        #pragma unroll
        for (int p = 0; p < 2; ++p) {
            int li = tid + p * 256;
            int krow = li >> 4, nc = (li & 15) << 2;
            int gk = k0 + krow;
            float4 bv = make_float4(0.f, 0.f, 0.f, 0.f);
            if (gk < K) {
                bv = *(const float4*)(Bm + (size_t)gk * NN + n0 + nc);
                if (rowscale) {
                    float dsc = rowscale[gk];
                    bv.x *= dsc; bv.y *= dsc; bv.z *= dsc; bv.w *= dsc;
                }
            }
            *(float4*)&Bs[krow][nc] = bv;
        }
        __syncthreads();
        #pragma unroll 8
        for (int kk = 0; kk < 32; ++kk) {
            float4 a4 = *(const float4*)&As[kk][ty << 2];
            float4 b4 = *(const float4*)&Bs[kk][tx << 2];
            float av[4] = {a4.x, a4.y, a4.z, a4.w};
            float bvv[4] = {b4.x, b4.y, b4.z, b4.w};
            #pragma unroll
            for (int i = 0; i < 4; ++i)
                #pragma unroll
                for (int j = 0; j < 4; ++j)
                    acc[i][j] += av[i] * bvv[j];
        }
        __syncthreads();
    }
    const float pv = (mode >= 2) ? par[sidx] : 0.f;
    #pragma unroll
    for (int i = 0; i < 4; ++i) {
        int gm = m0 + (ty << 2) + i;
        if (gm >= M) continue;
        float* cp = C + (size_t)gm * NN + n0 + (tx << 2);
        float4 v = make_float4(acc[i][0], acc[i][1], acc[i][2], acc[i][3]);
        if (mode >= 1) {
            v.x = v.x > 0.f ? v.x : 0.1f * v.x;
            v.y = v.y > 0.f ? v.y : 0.1f * v.y;
            v.z = v.z > 0.f ? v.z : 0.1f * v.z;
            v.w = v.w > 0.f ? v.w : 0.1f * v.w;
        }
        if (mode == 2) { v.x *= pv; v.y *= pv; v.z *= pv; v.w *= pv; }
        if (mode == 3) {
            float4 o = *(const float4*)cp;
            v.x = o.x + pv * v.x; v.y = o.y + pv * v.y;
            v.z = o.z + pv * v.z; v.w = o.w + pv * v.w;
        }
        *(float4*)cp = v;
    }
}

// ---------------- final MLP head ----------------
__global__ __launch_bounds__(256) void mlp_kernel(
    const float* __restrict__ Xf, const float* __restrict__ hyper,
    const float* __restrict__ W1m, const float* __restrict__ b1m,
    const float* __restrict__ W2m, const float* __restrict__ b2m,
    float* __restrict__ out)
{
    __shared__ float w1s[256], b1s[16], w2s[16];
    int tid = threadIdx.x;
    w1s[tid] = W1m[tid];
    if (tid < 16) { b1s[tid] = b1m[tid]; w2s[tid] = W2m[tid]; }
    __syncthreads();
    int g = blockIdx.x * 256 + tid;                // (b*N+n)*T + t, 256000 total
    int t = g & 15;
    int r = g >> 4;
    int b = r / Nn, n = r % Nn;
    size_t base = (size_t)n * 1024 + (size_t)b * 128 + t * 8;
    float c[16];
    #pragma unroll
    for (int j = 0; j < 8; ++j) { c[j] = Xf[base + j]; c[8 + j] = hyper[base + j]; }
    float acc = b2m[0];
    #pragma unroll
    for (int hh = 0; hh < 16; ++hh) {
        float hs = b1s[hh];
        #pragma unroll
        for (int cc = 0; cc < 16; ++cc) hs += c[cc] * w1s[cc * 16 + hh];
        acc += fmaxf(hs, 0.f) * w2s[hh];
    }
    out[g] = acc;
}

extern "C" void kernel_launch(void* const* d_in, const int* in_sizes, int n_in,
                              void* d_out, int out_size, void* d_ws, size_t ws_size,
                              hipStream_t stream)
{
    const float* inputs = (const float*)d_in[0];
    const float* emb_W  = (const float*)d_in[1];
    const float* emb_b  = (const float*)d_in[2];
    const float* W1     = (const float*)d_in[3];
    const float* U1     = (const float*)d_in[4];
    const float* b1     = (const float*)d_in[5];
    const float* ln1_g  = (const float*)d_in[6];
    const float* ln1_b  = (const float*)d_in[7];
    const float* W2     = (const float*)d_in[8];
    const float* U2     = (const float*)d_in[9];
    const float* b2     = (const float*)d_in[10];
    const float* Wq     = (const float*)d_in[11];
    const float* Wk     = (const float*)d_in[12];
    const float* Wv     = (const float*)d_in[13];
    const float* Wo     = (const float*)d_in[14];
    const float* ln2_g  = (const float*)d_in[15];
    const float* ln2_b  = (const float*)d_in[16];
    const float* par    = (const float*)d_in[17];
    const float* theta1 = (const float*)d_in[18];
    const float* diag1  = (const float*)d_in[19];
    const float* theta2 = (const float*)d_in[20];
    const float* diag2  = (const float*)d_in[21];
    const float* mlp1_W = (const float*)d_in[22];
    const float* mlp1_b = (const float*)d_in[23];
    const float* mlp2_W = (const float*)d_in[24];
    const float* mlp2_b = (const float*)d_in[25];
    const float* wav    = (const float*)d_in[26];
    const float* winv   = (const float*)d_in[27];
    float* ws  = (float*)d_ws;
    float* out = (float*)d_out;

    // workspace layout (floats), aggressive aliasing of dead buffers:
    float* xemb  = ws + 0;         // 4,096,000 [B,N,T,E]
    float* h1    = ws + 4096000;   // 4,096,000 [B,N,T,H1]
    float* o1    = ws + 0;         // 4,096,000 (aliases xemb; dead after lstm1)
    float* h2    = ws + 4096000;   // 2,048,000 (aliases h1; dead after ln1)
    float* qb    = ws + 6144000;   // 4096 [B,NH,T,DK]
    float* kb    = ws + 6148096;
    float* vb    = ws + 6152192;
    float* ctx   = ws + 6156288;   // 4096 [B,T,32]
    float* resid = ws + 6160384;   // 2,048,000 [B,T,DM]
    float* Xf    = ws + 8208384;   // 2,048,000 [N, B*D] — live to the end
    float* X1    = ws + 0;         // 2,048,000 (aliases o1; dead after lstm2)
    float* G     = ws + 2048000;   // 2,048,000
    float* Fb    = ws + 4096000;   // 2,048,000 (aliases h2; dead after ln2)
    float* X2    = ws + 6144000;   // 2,048,000 (aliases qkv+resid; dead after ln2)
    float* hyper = ws + 10256384;  // 2,048,000 -> peak 12,304,384 floats ≈ 49.2 MB

    embed_kernel<<<16000, 256, 0, stream>>>(inputs, emb_W, emb_b, xemb);
    lstm1_kernel<<<4000, 256, 0, stream>>>(xemb, W1, U1, b1, h1);
    ln1_kernel<<<128, 256, 0, stream>>>(h1, ln1_g, ln1_b, o1);
    lstm2_kernel<<<2000, 256, 0, stream>>>(o1, W2, U2, b2, h2);
    qkv_kernel<<<128, 256, 0, stream>>>(h2, Wq, Wk, Wv, qb, kb, vb);
    attn_kernel<<<32, 256, 0, stream>>>(qb, kb, vb, ctx);
    ln2_kernel<<<128, 256, 0, stream>>>(h2, ctx, Wo, ln2_g, ln2_b, resid, Xf);
    theta_kernel<<<dim3(2000, 8), 128, 0, stream>>>(Xf, theta1, X1);

    dim3 ggrid(32, 16);
    for (int s = 0; s < Ss; ++s) {
        const float* Ws    = wav  + (size_t)s * Nn * Nn;
        const float* Winvs = winv + (size_t)s * Nn * Nn;
        hgemm_f32<<<ggrid, 256, 0, stream>>>(Winvs, X1, G, nullptr, nullptr, 0, 0, Nn, Nn);
        hgemm_f32<<<ggrid, 256, 0, stream>>>(Ws, G, Fb, diag1, nullptr, 0, 1, Nn, Nn);
        theta_kernel<<<dim3(2000, 8), 128, 0, stream>>>(Fb, theta2, X2);
        hgemm_f32<<<ggrid, 256, 0, stream>>>(Winvs, X2, G, nullptr, nullptr, 0, 0, Nn, Nn);
        hgemm_f32<<<ggrid, 256, 0, stream>>>(Ws, G, hyper, diag2, par, s,
                                             (s == 0) ? 2 : 3, Nn, Nn);
    }
    mlp_kernel<<<1000, 256, 0, stream>>>(Xf, hyper, mlp1_W, mlp1_b, mlp2_W, mlp2_b, out);
}

// Round 3
// 977.409 us; speedup vs baseline: 7.5647x; 7.5647x over previous
//
#include <hip/hip_runtime.h>
#include <cstddef>

#define Bb 8
#define Ss 4
#define Nn 2000
#define Tt 16
#define Ee 16
#define H1 16
#define H2 8
#define DMm 16000

typedef __bf16 bf16;
typedef bf16 bf16x8 __attribute__((ext_vector_type(8)));
typedef float f32x4 __attribute__((ext_vector_type(4)));
#define GAS __attribute__((address_space(1)))
#define LAS __attribute__((address_space(3)))

// ---------------- embed ----------------
__global__ __launch_bounds__(256) void embed_kernel(
    const float* __restrict__ in, const float* __restrict__ eW,
    const float* __restrict__ eb, float* __restrict__ x)
{
    int g = blockIdx.x * 256 + threadIdx.x;
    int e = g & 15;
    int row = g >> 4;
    const float* ip = in + (size_t)row * 10;
    float a = eb[e];
    #pragma unroll
    for (int f = 0; f < 10; ++f) a += ip[f] * eW[f * 16 + e];
    x[g] = a;
}

// ---------------- LSTM1 ----------------
__global__ __launch_bounds__(256) void lstm1_kernel(
    const float* __restrict__ x, const float* __restrict__ W1,
    const float* __restrict__ U1, const float* __restrict__ b1,
    float* __restrict__ h1)
{
    int tid = threadIdx.x;
    int lane = tid & 63, wid = tid >> 6;
    int p = blockIdx.x * 4 + wid;
    float wcol[16], ucol[16];
    #pragma unroll
    for (int e = 0; e < 16; ++e) wcol[e] = W1[e * 64 + lane];
    #pragma unroll
    for (int k = 0; k < 16; ++k) ucol[k] = U1[k * 64 + lane];
    float bj = b1[lane];
    float hv = 0.f, cv = 0.f;
    const float* xp = x + (size_t)p * (Tt * Ee);
    float* hp = h1 + (size_t)p * (Tt * H1);
    for (int t = 0; t < Tt; ++t) {
        float xv = (lane < 16) ? xp[t * 16 + lane] : 0.f;
        float z = bj;
        #pragma unroll
        for (int e = 0; e < 16; ++e) z += __shfl(xv, e) * wcol[e];
        #pragma unroll
        for (int k = 0; k < 16; ++k) z += __shfl(hv, k) * ucol[k];
        float fz = __shfl(z, (lane + 16) & 63);
        float gz = __shfl(z, (lane + 32) & 63);
        float oz = __shfl(z, (lane + 48) & 63);
        if (lane < 16) {
            float ig = 1.f / (1.f + __expf(-z));
            float fg = 1.f / (1.f + __expf(-fz));
            float og = 1.f / (1.f + __expf(-oz));
            cv = fg * cv + ig * tanhf(gz);
            hv = og * tanhf(cv);
            hp[t * 16 + lane] = hv;
        }
    }
}

// ---------------- LSTM2 ----------------
__global__ __launch_bounds__(256) void lstm2_kernel(
    const float* __restrict__ o1, const float* __restrict__ W2,
    const float* __restrict__ U2, const float* __restrict__ b2,
    float* __restrict__ h2)
{
    int tid = threadIdx.x;
    int lane = tid & 63, wid = tid >> 6;
    int j = lane & 31, half = lane >> 5, base = half << 5;
    int p = blockIdx.x * 8 + wid * 2 + half;
    float wcol[16], ucol[8];
    #pragma unroll
    for (int e = 0; e < 16; ++e) wcol[e] = W2[e * 32 + j];
    #pragma unroll
    for (int k = 0; k < 8; ++k) ucol[k] = U2[k * 32 + j];
    float bj = b2[j];
    float hv = 0.f, cv = 0.f;
    const float* op = o1 + (size_t)p * (Tt * H1);
    float* hp = h2 + (size_t)p * (Tt * H2);
    for (int t = 0; t < Tt; ++t) {
        float xv = (j < 16) ? op[t * 16 + j] : 0.f;
        float z = bj;
        #pragma unroll
        for (int e = 0; e < 16; ++e) z += __shfl(xv, base + e) * wcol[e];
        #pragma unroll
        for (int k = 0; k < 8; ++k) z += __shfl(hv, base + k) * ucol[k];
        float fz = __shfl(z, base + ((j + 8) & 31));
        float gz = __shfl(z, base + ((j + 16) & 31));
        float oz = __shfl(z, base + ((j + 24) & 31));
        if (j < 8) {
            float ig = 1.f / (1.f + __expf(-z));
            float fg = 1.f / (1.f + __expf(-fz));
            float og = 1.f / (1.f + __expf(-oz));
            cv = fg * cv + ig * tanhf(gz);
            hv = og * tanhf(cv);
            hp[t * 8 + j] = hv;
        }
    }
}

__device__ __forceinline__ void block_reduce2(float& a, float& b)
{
    #pragma unroll
    for (int off = 32; off; off >>= 1) {
        a += __shfl_xor(a, off);
        b += __shfl_xor(b, off);
    }
    __shared__ float r[8];
    int tid = threadIdx.x;
    if ((tid & 63) == 0) { r[tid >> 6] = a; r[4 + (tid >> 6)] = b; }
    __syncthreads();
    a = r[0] + r[1] + r[2] + r[3];
    b = r[4] + r[5] + r[6] + r[7];
}

// ---------------- LN1 ----------------
__global__ __launch_bounds__(256) void ln1_kernel(
    const float* __restrict__ h1, const float* __restrict__ g,
    const float* __restrict__ bta, float* __restrict__ o1)
{
    int b = blockIdx.x >> 4, t = blockIdx.x & 15;
    int tid = threadIdx.x;
    float sum = 0.f, sq = 0.f;
    for (int i = tid; i < Nn * H1; i += 256) {
        int n = i >> 4, j = i & 15;
        float v = h1[(((size_t)b * Nn + n) * Tt + t) * H1 + j];
        sum += v; sq += v * v;
    }
    block_reduce2(sum, sq);
    float mu = sum * (1.f / (Nn * H1));
    float var = sq * (1.f / (Nn * H1)) - mu * mu;
    float rstd = rsqrtf(var + 1e-5f);
    for (int i = tid; i < Nn * H1; i += 256) {
        int n = i >> 4, j = i & 15;
        size_t idx = (((size_t)b * Nn + n) * Tt + t) * H1 + j;
        o1[idx] = (h1[idx] - mu) * rstd * g[i] + bta[i];
    }
}

// ---------------- transpose h2 -> enc [B*T][16000] ----------------
__global__ __launch_bounds__(256) void transp_kernel(
    const float* __restrict__ h2, float* __restrict__ enc)
{
    int g = blockIdx.x * 256 + threadIdx.x;   // 2,048,000
    int r = g & 127;                          // t*8+j
    int p = g >> 7;                           // b*2000+n
    int b = p / Nn, n = p % Nn;
    enc[(size_t)(b * 16 + (r >> 3)) * DMm + n * 8 + (r & 7)] = h2[g];
}

// ---------------- QKV split-K partials ----------------
// grid (32 kslices, 8 row-groups of 16 bt), block 192
__global__ __launch_bounds__(192) void qkv_part_kernel(
    const float* __restrict__ enc, const float* __restrict__ Wq,
    const float* __restrict__ Wk, const float* __restrict__ Wv,
    float* __restrict__ partial)
{
    __shared__ float encT[500 * 16];          // [kk][r]
    int ks = blockIdx.x, btg = blockIdx.y;
    int tid = threadIdx.x;
    int k0 = ks * 500;
    for (int idx = tid; idx < 8000; idx += 192) {
        int kk = idx >> 4, r = idx & 15;
        encT[idx] = enc[(size_t)(btg * 16 + r) * DMm + k0 + kk];
    }
    __syncthreads();
    int c = tid % 96, rg = tid / 96;
    int cc = c & 31;
    const float* W = (c < 32) ? Wq : ((c < 64) ? Wk : Wv);
    float acc[8] = {};
    for (int kk = 0; kk < 500; ++kk) {
        float w = W[(size_t)(k0 + kk) * 32 + cc];
        const float* e = &encT[kk * 16 + rg * 8];
        #pragma unroll
        for (int r8 = 0; r8 < 8; ++r8) acc[r8] += e[r8] * w;
    }
    #pragma unroll
    for (int r8 = 0; r8 < 8; ++r8)
        partial[((size_t)ks * 128 + btg * 16 + rg * 8 + r8) * 96 + c] = acc[r8];
}

// ---------------- QKV reduce ----------------
__global__ __launch_bounds__(256) void qkv_red_kernel(
    const float* __restrict__ partial, float* __restrict__ qb,
    float* __restrict__ kb, float* __restrict__ vb)
{
    int o = blockIdx.x * 256 + threadIdx.x;   // 12288
    int bt = o / 96, c = o % 96;
    float v = 0.f;
    for (int ks = 0; ks < 32; ++ks) v += partial[(size_t)ks * 12288 + o];
    int b = bt >> 4, t = bt & 15;
    int cc = c & 31, h = cc >> 3, dk = cc & 7;
    float* dst = (c < 32) ? qb : ((c < 64) ? kb : vb);
    dst[(((size_t)b * 4 + h) * 16 + t) * 8 + dk] = v;
}

// ---------------- attention ----------------
__global__ __launch_bounds__(256) void attn_kernel(
    const float* __restrict__ qb, const float* __restrict__ kb,
    const float* __restrict__ vb, float* __restrict__ ctx)
{
    int bh = blockIdx.x;
    int b = bh >> 2, h = bh & 3;
    __shared__ float qs[128], ks[128], vs[128], att[16][16];
    int tid = threadIdx.x;
    if (tid < 128) {
        qs[tid] = qb[(size_t)bh * 128 + tid];
        ks[tid] = kb[(size_t)bh * 128 + tid];
        vs[tid] = vb[(size_t)bh * 128 + tid];
    }
    __syncthreads();
    int qt = tid >> 4, kt = tid & 15;
    float s = -1e9f;
    if (kt <= qt) {
        float d = 0.f;
        #pragma unroll
        for (int x = 0; x < 8; ++x) d += qs[qt * 8 + x] * ks[kt * 8 + x];
        s = d * 0.35355339059327373f;
    }
    float mx = s;
    #pragma unroll
    for (int off = 8; off; off >>= 1) mx = fmaxf(mx, __shfl_xor(mx, off, 16));
    float p = __expf(s - mx);
    float sm = p;
    #pragma unroll
    for (int off = 8; off; off >>= 1) sm += __shfl_xor(sm, off, 16);
    att[qt][kt] = p / sm;
    __syncthreads();
    if (tid < 128) {
        int q2 = tid >> 3, dv = tid & 7;
        float cacc = 0.f;
        #pragma unroll
        for (int k2 = 0; k2 < 16; ++k2) cacc += att[q2][k2] * vs[k2 * 8 + dv];
        ctx[((size_t)b * 16 + q2) * 32 + h * 8 + dv] = cacc;
    }
}

// ---------------- ctx @ Wo -> resid2 [BT][16000] ----------------
__global__ __launch_bounds__(256) void ctxwo_kernel(
    const float* __restrict__ ctx, const float* __restrict__ Wo,
    float* __restrict__ resid2)
{
    int bt = blockIdx.y;
    int m = blockIdx.x * 256 + threadIdx.x;
    __shared__ float cs[32];
    if (threadIdx.x < 32) cs[threadIdx.x] = ctx[(size_t)bt * 32 + threadIdx.x];
    __syncthreads();
    if (m < DMm) {
        float acc = 0.f;
        #pragma unroll
        for (int j = 0; j < 32; ++j) acc += cs[j] * Wo[(size_t)j * DMm + m];
        resid2[(size_t)bt * DMm + m] = acc;
    }
}

// ---------------- LN2: writes Xf [2000][1024] fp32 and Xft [1024][2048] bf16 ----------------
__global__ __launch_bounds__(256) void ln2_kernel(
    const float* __restrict__ enc, float* __restrict__ resid2,
    const float* __restrict__ g2, const float* __restrict__ b2v,
    float* __restrict__ Xf, bf16* __restrict__ Xft)
{
    int bt = blockIdx.x;
    int b = bt >> 4, t = bt & 15;
    int tid = threadIdx.x;
    float sum = 0.f, sq = 0.f;
    for (int m = tid; m < DMm; m += 256) {
        float v = enc[(size_t)bt * DMm + m] + resid2[(size_t)bt * DMm + m];
        resid2[(size_t)bt * DMm + m] = v;
        sum += v; sq += v * v;
    }
    block_reduce2(sum, sq);
    float mu = sum * (1.f / DMm);
    float var = sq * (1.f / DMm) - mu * mu;
    float rstd = rsqrtf(var + 1e-5f);
    for (int m = tid; m < DMm; m += 256) {
        float v = resid2[(size_t)bt * DMm + m];
        float y = (v - mu) * rstd * g2[m] + b2v[m];
        int n = m >> 3, j = m & 7;
        Xf[(size_t)n * 1024 + b * 128 + t * 8 + j] = y;
        Xft[(size_t)(b * 128 + t * 8 + j) * 2048 + n] = (bf16)y;
    }
}

// ---------------- fp32 -> bf16 with k-pad to 2016 (pad zero) ----------------
__global__ __launch_bounds__(256) void cvt_pad_kernel(
    const float* __restrict__ src, bf16* __restrict__ dst)
{
    int row = blockIdx.y;                     // 8000 rows (4 s * 2000)
    int col = blockIdx.x * 256 + threadIdx.x; // 0..2047
    if (col < 2016) {
        float v = (col < 2000) ? src[(size_t)row * 2000 + col] : 0.f;
        dst[(size_t)row * 2016 + col] = (bf16)v;
    }
}

// ---------------- zero pad cols [2000,2048) of activation buffers ----------------
__global__ __launch_bounds__(64) void zero_pad_kernel(
    bf16* __restrict__ Xft, bf16* __restrict__ X1b, bf16* __restrict__ Gb,
    bf16* __restrict__ Fb, bf16* __restrict__ X2b)
{
    int row = blockIdx.x;                     // 14336
    int tid = threadIdx.x;
    if (tid >= 48) return;
    bf16* p;
    if (row < 1024) p = Xft + (size_t)row * 2048;
    else if (row < 2048) p = X1b + (size_t)(row - 1024) * 2048;
    else if (row < 6144) p = Gb + (size_t)(row - 2048) * 2048;
    else if (row < 10240) p = Fb + (size_t)(row - 6144) * 2048;
    else p = X2b + (size_t)(row - 10240) * 2048;
    p[2000 + tid] = (bf16)0.f;
}

// ---------------- theta transform: Out[b*128+d][m] = sum_d0 In[b*128+d0][m]*th[d0][d] ----------------
// grid (32 mchunks, 8 b, z), block 256
__global__ __launch_bounds__(256) void theta_t_kernel(
    const bf16* __restrict__ In, long sIn, const float* __restrict__ th,
    bf16* __restrict__ Out, long sOut)
{
    __shared__ bf16 intile[128 * 64];
    int m0 = blockIdx.x * 64, b = blockIdx.y, s = blockIdx.z;
    int tid = threadIdx.x;
    const bf16* Ib = In + (size_t)s * sIn + (size_t)b * 128 * 2048;
    #pragma unroll
    for (int p = 0; p < 4; ++p) {
        int cidx = p * 256 + tid;
        int row = cidx >> 3, ch = cidx & 7;
        *(uint4*)(intile + row * 64 + ch * 8) =
            *(const uint4*)(Ib + (size_t)row * 2048 + m0 + ch * 8);
    }
    __syncthreads();
    int mloc = tid & 63, dg = tid >> 6;
    float acc[32] = {};
    for (int d0 = 0; d0 < 128; ++d0) {
        float a = (float)intile[d0 * 64 + mloc];
        const float* tr = th + d0 * 128 + dg * 32;
        #pragma unroll
        for (int dd = 0; dd < 32; ++dd) acc[dd] += a * tr[dd];
    }
    int m = m0 + mloc;
    if (m < 2000) {
        bf16* Ob = Out + (size_t)s * sOut + (size_t)(b * 128 + dg * 32) * 2048 + m;
        #pragma unroll
        for (int dd = 0; dd < 32; ++dd) Ob[(size_t)dd * 2048] = (bf16)acc[dd];
    }
}

// ---------------- bf16 MFMA GEMM: Ct[n][m] = sum_k A[m][k]*Bt[n][k] ----------------
// A [2000][2016] bf16 per s, Bt [1024][2048] bf16 per s.
// mode 0: trans-store bf16, *rowscale[m]; mode 1: trans-store bf16, leaky;
// mode 2: normal-store bf16 [m][1024], leaky.
__global__ __launch_bounds__(256) void hgemm_bf16(
    const bf16* __restrict__ A, long sA,
    const bf16* __restrict__ Bt, long sB,
    bf16* __restrict__ C, long sC,
    const float* __restrict__ rowscale, int mode)
{
    __shared__ bf16 As[128 * 32];
    __shared__ bf16 Bs[128 * 32];
    const int tid = threadIdx.x;
    const int lane = tid & 63, wave = tid >> 6;
    const int m0 = blockIdx.x * 128, n0 = blockIdx.y * 128;
    const int s = blockIdx.z;
    const bf16* Abase = A + (size_t)s * sA;
    const bf16* Bbase = Bt + (size_t)s * sB;
    const int wr = wave >> 1, wc = wave & 1;
    const int fm = lane & 15, quad = lane >> 4;

    // staging chunk assignment: 512 16-B chunks per tile, 2 per thread
    const int c0 = wave * 128 + lane, c1 = c0 + 64;
    int rA0 = m0 + (c0 >> 2); if (rA0 > 1999) rA0 = 1999;
    int rA1 = m0 + (c1 >> 2); if (rA1 > 1999) rA1 = 1999;
    const bf16* a0p = Abase + (size_t)rA0 * 2016 + (c0 & 3) * 8;
    const bf16* a1p = Abase + (size_t)rA1 * 2016 + (c1 & 3) * 8;
    const bf16* b0p = Bbase + (size_t)(n0 + (c0 >> 2)) * 2048 + (c0 & 3) * 8;
    const bf16* b1p = Bbase + (size_t)(n0 + (c1 >> 2)) * 2048 + (c1 & 3) * 8;
    bf16* as0 = As + c0 * 8; bf16* as1 = As + c1 * 8;
    bf16* bs0 = Bs + c0 * 8; bf16* bs1 = Bs + c1 * 8;

    f32x4 acc[4][4] = {};
    for (int kt = 0; kt < 63; ++kt) {
        const int k0 = kt * 32;
        __builtin_amdgcn_global_load_lds((const GAS unsigned int*)(a0p + k0),
                                         (LAS unsigned int*)as0, 16, 0, 0);
        __builtin_amdgcn_global_load_lds((const GAS unsigned int*)(a1p + k0),
                                         (LAS unsigned int*)as1, 16, 0, 0);
        __builtin_amdgcn_global_load_lds((const GAS unsigned int*)(b0p + k0),
                                         (LAS unsigned int*)bs0, 16, 0, 0);
        __builtin_amdgcn_global_load_lds((const GAS unsigned int*)(b1p + k0),
                                         (LAS unsigned int*)bs1, 16, 0, 0);
        __syncthreads();
        bf16x8 af[4], bfv[4];
        #pragma unroll
        for (int i = 0; i < 4; ++i)
            af[i] = *(const bf16x8*)(As + (wr * 64 + i * 16 + fm) * 32 + quad * 8);
        #pragma unroll
        for (int j = 0; j < 4; ++j)
            bfv[j] = *(const bf16x8*)(Bs + (wc * 64 + j * 16 + fm) * 32 + quad * 8);
        #pragma unroll
        for (int i = 0; i < 4; ++i)
            #pragma unroll
            for (int j = 0; j < 4; ++j)
                acc[i][j] = __builtin_amdgcn_mfma_f32_16x16x32_bf16(
                    af[i], bfv[j], acc[i][j], 0, 0, 0);
        __syncthreads();
    }

    const int fm4 = quad * 4;
    if (mode < 2) {
        #pragma unroll
        for (int i = 0; i < 4; ++i) {
            int m = m0 + wr * 64 + i * 16 + fm4;
            if (m >= 2000) continue;
            #pragma unroll
            for (int j = 0; j < 4; ++j) {
                int n = n0 + wc * 64 + j * 16 + fm;
                f32x4 v = acc[i][j];
                if (mode == 0) {
                    float4 rs = *(const float4*)(rowscale + m);
                    v[0] *= rs.x; v[1] *= rs.y; v[2] *= rs.z; v[3] *= rs.w;
                } else {
                    v[0] = v[0] > 0.f ? v[0] : 0.1f * v[0];
                    v[1] = v[1] > 0.f ? v[1] : 0.1f * v[1];
                    v[2] = v[2] > 0.f ? v[2] : 0.1f * v[2];
                    v[3] = v[3] > 0.f ? v[3] : 0.1f * v[3];
                }
                bf16 pk[4] = {(bf16)v[0], (bf16)v[1], (bf16)v[2], (bf16)v[3]};
                *(uint2*)(C + (size_t)s * sC + (size_t)n * 2048 + m) = *(uint2*)pk;
            }
        }
    } else {
        #pragma unroll
        for (int i = 0; i < 4; ++i) {
            int mb = m0 + wr * 64 + i * 16 + fm4;
            #pragma unroll
            for (int j = 0; j < 4; ++j) {
                int n = n0 + wc * 64 + j * 16 + fm;
                #pragma unroll
                for (int r = 0; r < 4; ++r) {
                    int m = mb + r;
                    if (m < 2000) {
                        float x = acc[i][j][r];
                        x = x > 0.f ? x : 0.1f * x;
                        C[(size_t)s * sC + (size_t)m * 1024 + n] = (bf16)x;
                    }
                }
            }
        }
    }
}

// ---------------- final MLP (fuses par-weighted sum over s) ----------------
__global__ __launch_bounds__(256) void mlp_kernel(
    const float* __restrict__ Xf, const bf16* __restrict__ F2,
    const float* __restrict__ par, const float* __restrict__ W1m,
    const float* __restrict__ b1m, const float* __restrict__ W2m,
    const float* __restrict__ b2m, float* __restrict__ out)
{
    __shared__ float w1s[256], b1s[16], w2s[16];
    int tid = threadIdx.x;
    w1s[tid] = W1m[tid];
    if (tid < 16) { b1s[tid] = b1m[tid]; w2s[tid] = W2m[tid]; }
    __syncthreads();
    int g = blockIdx.x * 256 + tid;           // 256000
    int t = g & 15;
    int r = g >> 4;
    int b = r / Nn, n = r % Nn;
    size_t base = (size_t)n * 1024 + b * 128 + t * 8;
    float p0 = par[0], p1 = par[1], p2 = par[2], p3 = par[3];
    float c[16];
    #pragma unroll
    for (int j = 0; j < 8; ++j) {
        c[j] = Xf[base + j];
        c[8 + j] = p0 * (float)F2[base + j]
                 + p1 * (float)F2[2048000 + base + j]
                 + p2 * (float)F2[4096000 + base + j]
                 + p3 * (float)F2[6144000 + base + j];
    }
    float acc = b2m[0];
    #pragma unroll
    for (int hh = 0; hh < 16; ++hh) {
        float hs = b1s[hh];
        #pragma unroll
        for (int cc = 0; cc < 16; ++cc) hs += c[cc] * w1s[cc * 16 + hh];
        acc += fmaxf(hs, 0.f) * w2s[hh];
    }
    out[g] = acc;
}

extern "C" void kernel_launch(void* const* d_in, const int* in_sizes, int n_in,
                              void* d_out, int out_size, void* d_ws, size_t ws_size,
                              hipStream_t stream)
{
    const float* inputs = (const float*)d_in[0];
    const float* emb_W  = (const float*)d_in[1];
    const float* emb_b  = (const float*)d_in[2];
    const float* W1     = (const float*)d_in[3];
    const float* U1     = (const float*)d_in[4];
    const float* b1     = (const float*)d_in[5];
    const float* ln1_g  = (const float*)d_in[6];
    const float* ln1_b  = (const float*)d_in[7];
    const float* W2     = (const float*)d_in[8];
    const float* U2     = (const float*)d_in[9];
    const float* b2     = (const float*)d_in[10];
    const float* Wq     = (const float*)d_in[11];
    const float* Wk     = (const float*)d_in[12];
    const float* Wv     = (const float*)d_in[13];
    const float* Wo     = (const float*)d_in[14];
    const float* ln2_g  = (const float*)d_in[15];
    const float* ln2_b  = (const float*)d_in[16];
    const float* par    = (const float*)d_in[17];
    const float* theta1 = (const float*)d_in[18];
    const float* diag1  = (const float*)d_in[19];
    const float* theta2 = (const float*)d_in[20];
    const float* diag2  = (const float*)d_in[21];
    const float* mlp1_W = (const float*)d_in[22];
    const float* mlp1_b = (const float*)d_in[23];
    const float* mlp2_W = (const float*)d_in[24];
    const float* mlp2_b = (const float*)d_in[25];
    const float* wav    = (const float*)d_in[26];
    const float* winv   = (const float*)d_in[27];
    float* ws  = (float*)d_ws;
    float* out = (float*)d_out;

    // ---- workspace layout (float offsets) ----
    float* xemb   = ws + 0;          // [0, 4,096,000)           stage A
    float* h1     = ws + 4096000;    // [4,096,000, 8,192,000)
    float* o1     = ws + 0;          // aliases xemb (dead)
    float* h2     = ws + 8192000;    // [8,192,000, 10,240,000)
    float* enc    = ws + 10240000;   // [10,240,000, 12,288,000)
    float* qpart  = ws + 12288000;   // 393,216
    float* qb     = ws + 12681216;   // 4096
    float* kb     = ws + 12685312;
    float* vb     = ws + 12689408;
    float* ctx    = ws + 12693504;
    float* resid2 = ws + 4096000;    // aliases h1 (dead after ln1)
    float* Xf     = ws + 16128000;   // [16,128,000, 18,176,000) fp32, live to end
    bf16*  Xft    = (bf16*)(ws + 18176000);  // [1024][2048] bf16
    bf16*  wavb   = (bf16*)(ws + 0);         // [4][2000][2016] bf16 (after ln2)
    bf16*  winvb  = (bf16*)(ws + 8064000);   // same size
    bf16*  X1b    = (bf16*)(ws + 19224576);  // [1024][2048]
    bf16*  Gb     = (bf16*)(ws + 20273152);  // [4][1024][2048]
    bf16*  Fb     = (bf16*)(ws + 24467456);  // [4][1024][2048]
    bf16*  X2b    = (bf16*)(ws + 28661760);  // [4][1024][2048]
    bf16*  F2b    = (bf16*)(ws + 24467456);  // [4][2000][1024] aliases Fb (dead after theta2)

    // ---- stage A ----
    embed_kernel<<<16000, 256, 0, stream>>>(inputs, emb_W, emb_b, xemb);
    lstm1_kernel<<<4000, 256, 0, stream>>>(xemb, W1, U1, b1, h1);
    ln1_kernel<<<128, 256, 0, stream>>>(h1, ln1_g, ln1_b, o1);
    lstm2_kernel<<<2000, 256, 0, stream>>>(o1, W2, U2, b2, h2);
    transp_kernel<<<8000, 256, 0, stream>>>(h2, enc);
    qkv_part_kernel<<<dim3(32, 8), 192, 0, stream>>>(enc, Wq, Wk, Wv, qpart);
    qkv_red_kernel<<<48, 256, 0, stream>>>(qpart, qb, kb, vb);
    attn_kernel<<<32, 256, 0, stream>>>(qb, kb, vb, ctx);
    ctxwo_kernel<<<dim3(63, 128), 256, 0, stream>>>(ctx, Wo, resid2);
    ln2_kernel<<<128, 256, 0, stream>>>(enc, resid2, ln2_g, ln2_b, Xf, Xft);

    // ---- stage B: bf16 conversion + padding ----
    cvt_pad_kernel<<<dim3(8, 8000), 256, 0, stream>>>(wav, wavb);
    cvt_pad_kernel<<<dim3(8, 8000), 256, 0, stream>>>(winv, winvb);
    zero_pad_kernel<<<14336, 64, 0, stream>>>(Xft, X1b, Gb, Fb, X2b);

    // ---- hypergraph wavelet block (batched over s in grid-z) ----
    const long sW = 4032000;     // wavelet slab stride (bf16)
    const long sAct = 2097152;   // [1024][2048] bf16
    const long sF2 = 2048000;    // [2000][1024] bf16
    theta_t_kernel<<<dim3(32, 8, 1), 256, 0, stream>>>(Xft, 0, theta1, X1b, 0);
    hgemm_bf16<<<dim3(16, 8, 4), 256, 0, stream>>>(winvb, sW, X1b, 0, Gb, sAct, diag1, 0);
    hgemm_bf16<<<dim3(16, 8, 4), 256, 0, stream>>>(wavb, sW, Gb, sAct, Fb, sAct, nullptr, 1);
    theta_t_kernel<<<dim3(32, 8, 4), 256, 0, stream>>>(Fb, sAct, theta2, X2b, sAct);
    hgemm_bf16<<<dim3(16, 8, 4), 256, 0, stream>>>(winvb, sW, X2b, sAct, Gb, sAct, diag2, 0);
    hgemm_bf16<<<dim3(16, 8, 4), 256, 0, stream>>>(wavb, sW, Gb, sAct, F2b, sF2, nullptr, 2);

    // ---- head ----
    mlp_kernel<<<1000, 256, 0, stream>>>(Xf, F2b, par, mlp1_W, mlp1_b,
                                         mlp2_W, mlp2_b, out);
}

// Round 5
// 731.558 us; speedup vs baseline: 10.1069x; 1.3361x over previous
//
#include <hip/hip_runtime.h>
#include <cstddef>

#define Bb 8
#define Ss 4
#define Nn 2000
#define Tt 16
#define Ee 16
#define H1 16
#define H2 8
#define DMm 16000

typedef __bf16 bf16;
typedef bf16 bf16x8 __attribute__((ext_vector_type(8)));
typedef float f32x4 __attribute__((ext_vector_type(4)));
#define GAS __attribute__((address_space(1)))
#define LAS __attribute__((address_space(3)))

// ---------------- embed ----------------
__global__ __launch_bounds__(256) void embed_kernel(
    const float* __restrict__ in, const float* __restrict__ eW,
    const float* __restrict__ eb, float* __restrict__ x)
{
    int g = blockIdx.x * 256 + threadIdx.x;
    int e = g & 15;
    int row = g >> 4;
    const float* ip = in + (size_t)row * 10;
    float a = eb[e];
    #pragma unroll
    for (int f = 0; f < 10; ++f) a += ip[f] * eW[f * 16 + e];
    x[g] = a;
}

// ---------------- LSTM1 ----------------
__global__ __launch_bounds__(256) void lstm1_kernel(
    const float* __restrict__ x, const float* __restrict__ W1,
    const float* __restrict__ U1, const float* __restrict__ b1,
    float* __restrict__ h1)
{
    int tid = threadIdx.x;
    int lane = tid & 63, wid = tid >> 6;
    int p = blockIdx.x * 4 + wid;
    float wcol[16], ucol[16];
    #pragma unroll
    for (int e = 0; e < 16; ++e) wcol[e] = W1[e * 64 + lane];
    #pragma unroll
    for (int k = 0; k < 16; ++k) ucol[k] = U1[k * 64 + lane];
    float bj = b1[lane];
    float hv = 0.f, cv = 0.f;
    const float* xp = x + (size_t)p * (Tt * Ee);
    float* hp = h1 + (size_t)p * (Tt * H1);
    for (int t = 0; t < Tt; ++t) {
        float xv = (lane < 16) ? xp[t * 16 + lane] : 0.f;
        float z = bj;
        #pragma unroll
        for (int e = 0; e < 16; ++e) z += __shfl(xv, e) * wcol[e];
        #pragma unroll
        for (int k = 0; k < 16; ++k) z += __shfl(hv, k) * ucol[k];
        float fz = __shfl(z, (lane + 16) & 63);
        float gz = __shfl(z, (lane + 32) & 63);
        float oz = __shfl(z, (lane + 48) & 63);
        if (lane < 16) {
            float ig = 1.f / (1.f + __expf(-z));
            float fg = 1.f / (1.f + __expf(-fz));
            float og = 1.f / (1.f + __expf(-oz));
            cv = fg * cv + ig * tanhf(gz);
            hv = og * tanhf(cv);
            hp[t * 16 + lane] = hv;
        }
    }
}

// ---------------- LSTM2 ----------------
__global__ __launch_bounds__(256) void lstm2_kernel(
    const float* __restrict__ o1, const float* __restrict__ W2,
    const float* __restrict__ U2, const float* __restrict__ b2,
    float* __restrict__ h2)
{
    int tid = threadIdx.x;
    int lane = tid & 63, wid = tid >> 6;
    int j = lane & 31, half = lane >> 5, base = half << 5;
    int p = blockIdx.x * 8 + wid * 2 + half;
    float wcol[16], ucol[8];
    #pragma unroll
    for (int e = 0; e < 16; ++e) wcol[e] = W2[e * 32 + j];
    #pragma unroll
    for (int k = 0; k < 8; ++k) ucol[k] = U2[k * 32 + j];
    float bj = b2[j];
    float hv = 0.f, cv = 0.f;
    const float* op = o1 + (size_t)p * (Tt * H1);
    float* hp = h2 + (size_t)p * (Tt * H2);
    for (int t = 0; t < Tt; ++t) {
        float xv = (j < 16) ? op[t * 16 + j] : 0.f;
        float z = bj;
        #pragma unroll
        for (int e = 0; e < 16; ++e) z += __shfl(xv, base + e) * wcol[e];
        #pragma unroll
        for (int k = 0; k < 8; ++k) z += __shfl(hv, base + k) * ucol[k];
        float fz = __shfl(z, base + ((j + 8) & 31));
        float gz = __shfl(z, base + ((j + 16) & 31));
        float oz = __shfl(z, base + ((j + 24) & 31));
        if (j < 8) {
            float ig = 1.f / (1.f + __expf(-z));
            float fg = 1.f / (1.f + __expf(-fz));
            float og = 1.f / (1.f + __expf(-oz));
            cv = fg * cv + ig * tanhf(gz);
            hv = og * tanhf(cv);
            hp[t * 8 + j] = hv;
        }
    }
}

template<int NW>
__device__ __forceinline__ void block_reduce2t(float& a, float& b)
{
    #pragma unroll
    for (int off = 32; off; off >>= 1) {
        a += __shfl_xor(a, off);
        b += __shfl_xor(b, off);
    }
    __shared__ float r[2 * NW];
    int tid = threadIdx.x;
    if ((tid & 63) == 0) { r[tid >> 6] = a; r[NW + (tid >> 6)] = b; }
    __syncthreads();
    a = 0.f; b = 0.f;
    #pragma unroll
    for (int w = 0; w < NW; ++w) { a += r[w]; b += r[NW + w]; }
}

// ---------------- LN1 (1024 threads) ----------------
__global__ __launch_bounds__(1024) void ln1_kernel(
    const float* __restrict__ h1, const float* __restrict__ g,
    const float* __restrict__ bta, float* __restrict__ o1)
{
    int b = blockIdx.x >> 4, t = blockIdx.x & 15;
    int tid = threadIdx.x;
    float sum = 0.f, sq = 0.f;
    for (int i = tid; i < Nn * H1; i += 1024) {
        int n = i >> 4, j = i & 15;
        float v = h1[(((size_t)b * Nn + n) * Tt + t) * H1 + j];
        sum += v; sq += v * v;
    }
    block_reduce2t<16>(sum, sq);
    float mu = sum * (1.f / (Nn * H1));
    float var = sq * (1.f / (Nn * H1)) - mu * mu;
    float rstd = rsqrtf(var + 1e-5f);
    for (int i = tid; i < Nn * H1; i += 1024) {
        int n = i >> 4, j = i & 15;
        size_t idx = (((size_t)b * Nn + n) * Tt + t) * H1 + j;
        o1[idx] = (h1[idx] - mu) * rstd * g[i] + bta[i];
    }
}

// ---------------- transpose h2 -> enc [B*T][16000] ----------------
__global__ __launch_bounds__(256) void transp_kernel(
    const float* __restrict__ h2, float* __restrict__ enc)
{
    int g = blockIdx.x * 256 + threadIdx.x;   // 2,048,000
    int r = g & 127;
    int p = g >> 7;
    int b = p / Nn, n = p % Nn;
    enc[(size_t)(b * 16 + (r >> 3)) * DMm + n * 8 + (r & 7)] = h2[g];
}

// ---------------- QKV split-K partials ----------------
__global__ __launch_bounds__(192) void qkv_part_kernel(
    const float* __restrict__ enc, const float* __restrict__ Wq,
    const float* __restrict__ Wk, const float* __restrict__ Wv,
    float* __restrict__ partial)
{
    __shared__ float encT[500 * 16];
    int ks = blockIdx.x, btg = blockIdx.y;
    int tid = threadIdx.x;
    int k0 = ks * 500;
    for (int idx = tid; idx < 8000; idx += 192) {
        int kk = idx >> 4, r = idx & 15;
        encT[idx] = enc[(size_t)(btg * 16 + r) * DMm + k0 + kk];
    }
    __syncthreads();
    int c = tid % 96, rg = tid / 96;
    int cc = c & 31;
    const float* W = (c < 32) ? Wq : ((c < 64) ? Wk : Wv);
    float acc[8] = {};
    for (int kk = 0; kk < 500; ++kk) {
        float w = W[(size_t)(k0 + kk) * 32 + cc];
        const float* e = &encT[kk * 16 + rg * 8];
        #pragma unroll
        for (int r8 = 0; r8 < 8; ++r8) acc[r8] += e[r8] * w;
    }
    #pragma unroll
    for (int r8 = 0; r8 < 8; ++r8)
        partial[((size_t)ks * 128 + btg * 16 + rg * 8 + r8) * 96 + c] = acc[r8];
}

// ---------------- QKV reduce ----------------
__global__ __launch_bounds__(256) void qkv_red_kernel(
    const float* __restrict__ partial, float* __restrict__ qb,
    float* __restrict__ kb, float* __restrict__ vb)
{
    int o = blockIdx.x * 256 + threadIdx.x;   // 12288
    int bt = o / 96, c = o % 96;
    float v = 0.f;
    for (int ks = 0; ks < 32; ++ks) v += partial[(size_t)ks * 12288 + o];
    int b = bt >> 4, t = bt & 15;
    int cc = c & 31, h = cc >> 3, dk = cc & 7;
    float* dst = (c < 32) ? qb : ((c < 64) ? kb : vb);
    dst[(((size_t)b * 4 + h) * 16 + t) * 8 + dk] = v;
}

// ---------------- attention ----------------
__global__ __launch_bounds__(256) void attn_kernel(
    const float* __restrict__ qb, const float* __restrict__ kb,
    const float* __restrict__ vb, float* __restrict__ ctx)
{
    int bh = blockIdx.x;
    int b = bh >> 2, h = bh & 3;
    __shared__ float qs[128], ks[128], vs[128], att[16][16];
    int tid = threadIdx.x;
    if (tid < 128) {
        qs[tid] = qb[(size_t)bh * 128 + tid];
        ks[tid] = kb[(size_t)bh * 128 + tid];
        vs[tid] = vb[(size_t)bh * 128 + tid];
    }
    __syncthreads();
    int qt = tid >> 4, kt = tid & 15;
    float s = -1e9f;
    if (kt <= qt) {
        float d = 0.f;
        #pragma unroll
        for (int x = 0; x < 8; ++x) d += qs[qt * 8 + x] * ks[kt * 8 + x];
        s = d * 0.35355339059327373f;
    }
    float mx = s;
    #pragma unroll
    for (int off = 8; off; off >>= 1) mx = fmaxf(mx, __shfl_xor(mx, off, 16));
    float p = __expf(s - mx);
    float sm = p;
    #pragma unroll
    for (int off = 8; off; off >>= 1) sm += __shfl_xor(sm, off, 16);
    att[qt][kt] = p / sm;
    __syncthreads();
    if (tid < 128) {
        int q2 = tid >> 3, dv = tid & 7;
        float cacc = 0.f;
        #pragma unroll
        for (int k2 = 0; k2 < 16; ++k2) cacc += att[q2][k2] * vs[k2 * 8 + dv];
        ctx[((size_t)b * 16 + q2) * 32 + h * 8 + dv] = cacc;
    }
}

// ---------------- ctx @ Wo -> resid2 [BT][16000] ----------------
__global__ __launch_bounds__(256) void ctxwo_kernel(
    const float* __restrict__ ctx, const float* __restrict__ Wo,
    float* __restrict__ resid2)
{
    int bt = blockIdx.y;
    int m = blockIdx.x * 256 + threadIdx.x;
    __shared__ float cs[32];
    if (threadIdx.x < 32) cs[threadIdx.x] = ctx[(size_t)bt * 32 + threadIdx.x];
    __syncthreads();
    if (m < DMm) {
        float acc = 0.f;
        #pragma unroll
        for (int j = 0; j < 32; ++j) acc += cs[j] * Wo[(size_t)j * DMm + m];
        resid2[(size_t)bt * DMm + m] = acc;
    }
}

// ---------------- LN2: writes Xf fp32 [2000][1024] and Xfb bf16 [2048][1024] ----------------
__global__ __launch_bounds__(1024) void ln2_kernel(
    const float* __restrict__ enc, float* __restrict__ resid2,
    const float* __restrict__ g2, const float* __restrict__ b2v,
    float* __restrict__ Xf, bf16* __restrict__ Xfb)
{
    int bt = blockIdx.x;
    int b = bt >> 4, t = bt & 15;
    int tid = threadIdx.x;
    float sum = 0.f, sq = 0.f;
    for (int m = tid; m < DMm; m += 1024) {
        float v = enc[(size_t)bt * DMm + m] + resid2[(size_t)bt * DMm + m];
        resid2[(size_t)bt * DMm + m] = v;
        sum += v; sq += v * v;
    }
    block_reduce2t<16>(sum, sq);
    float mu = sum * (1.f / DMm);
    float var = sq * (1.f / DMm) - mu * mu;
    float rstd = rsqrtf(var + 1e-5f);
    for (int m = tid; m < DMm; m += 1024) {
        float v = resid2[(size_t)bt * DMm + m];
        float y = (v - mu) * rstd * g2[m] + b2v[m];
        int n = m >> 3, j = m & 7;
        size_t o = (size_t)n * 1024 + b * 128 + t * 8 + j;
        Xf[o] = y;
        Xfb[o] = (bf16)y;
    }
}

// ---------------- fp32 -> bf16 with k-pad to 2016, vectorized ----------------
__global__ __launch_bounds__(256) void cvt_pad_kernel(
    const float* __restrict__ src, bf16* __restrict__ dst)
{
    int row = blockIdx.x;                     // 8000 rows (4 s * 2000)
    int tid = threadIdx.x;
    if (tid >= 252) return;
    int col = tid * 8;
    bf16 pk[8];
    if (col < 2000) {
        float4 v0 = *(const float4*)(src + (size_t)row * 2000 + col);
        float4 v1 = *(const float4*)(src + (size_t)row * 2000 + col + 4);
        pk[0] = (bf16)v0.x; pk[1] = (bf16)v0.y; pk[2] = (bf16)v0.z; pk[3] = (bf16)v0.w;
        pk[4] = (bf16)v1.x; pk[5] = (bf16)v1.y; pk[6] = (bf16)v1.z; pk[7] = (bf16)v1.w;
    } else {
        #pragma unroll
        for (int i = 0; i < 8; ++i) pk[i] = (bf16)0.f;
    }
    *(uint4*)(dst + (size_t)row * 2016 + col) = *(uint4*)pk;
}

// ---------------- zero pad cols [2000,2048) of trans-layout activation buffers ----------------
__global__ __launch_bounds__(64) void zero_pad_kernel(
    bf16* __restrict__ X1b, bf16* __restrict__ Gb, bf16* __restrict__ X2b)
{
    int row = blockIdx.x;                     // 9216 rows total
    int tid = threadIdx.x;
    if (tid >= 48) return;
    bf16* p;
    if (row < 1024) p = X1b + (size_t)row * 2048;
    else if (row < 5120) p = Gb + (size_t)(row - 1024) * 2048;
    else p = X2b + (size_t)(row - 5120) * 2048;
    p[2000 + tid] = (bf16)0.f;
}

// ---------------- theta transpose+cast: thT[d][d0] = th[d0][d] ----------------
__global__ __launch_bounds__(256) void thcvt_kernel(
    const float* __restrict__ th1, const float* __restrict__ th2,
    bf16* __restrict__ th1T, bf16* __restrict__ th2T)
{
    int g = blockIdx.x * 256 + threadIdx.x;   // 16384
    int d = g >> 7, d0 = g & 127;
    th1T[g] = (bf16)th1[(size_t)d0 * 128 + d];
    th2T[g] = (bf16)th2[(size_t)d0 * 128 + d];
}

// ---------------- theta MFMA: Out[(b*128+d)][m] = sum_d0 Act[m][b*128+d0]*thT[d][d0] ----------------
// Act: [s][2048 rows][1024], Out: [s][1024][2048] trans-layout. K=128 single pass.
__global__ __launch_bounds__(256) void theta_mfma(
    const bf16* __restrict__ Act, long sAct, const bf16* __restrict__ thT,
    bf16* __restrict__ Out, long sOut)
{
    __shared__ bf16 As2[128 * 128];
    __shared__ bf16 Bs2[128 * 128];
    const int tid = threadIdx.x;
    const int lane = tid & 63, wave = tid >> 6;
    const int m0 = blockIdx.x * 128, b = blockIdx.y, s = blockIdx.z;
    const bf16* Ab = Act + (size_t)s * sAct + (size_t)m0 * 1024 + b * 128;
    // full tile = 128 rows x 128 bf16 = 2048 16-B chunks; 8 iters x 256 threads
    #pragma unroll
    for (int r = 0; r < 8; ++r) {
        int c = r * 256 + wave * 64 + lane;   // 0..2047
        int row = c >> 4, col8 = (c & 15) * 8;
        __builtin_amdgcn_global_load_lds(
            (const GAS unsigned int*)(Ab + (size_t)row * 1024 + col8),
            (LAS unsigned int*)(As2 + c * 8), 16, 0, 0);
        __builtin_amdgcn_global_load_lds(
            (const GAS unsigned int*)(thT + (size_t)row * 128 + col8),
            (LAS unsigned int*)(Bs2 + c * 8), 16, 0, 0);
    }
    __syncthreads();
    const int wr = wave >> 1, wc = wave & 1;
    const int fm = lane & 15, quad = lane >> 4;
    f32x4 acc[4][4] = {};
    #pragma unroll
    for (int ks = 0; ks < 4; ++ks) {
        bf16x8 af[4], bfv[4];
        #pragma unroll
        for (int i = 0; i < 4; ++i)
            af[i] = *(const bf16x8*)(As2 + (wr * 64 + i * 16 + fm) * 128 + ks * 32 + quad * 8);
        #pragma unroll
        for (int j = 0; j < 4; ++j)
            bfv[j] = *(const bf16x8*)(Bs2 + (wc * 64 + j * 16 + fm) * 128 + ks * 32 + quad * 8);
        #pragma unroll
        for (int i = 0; i < 4; ++i)
            #pragma unroll
            for (int j = 0; j < 4; ++j)
                acc[i][j] = __builtin_amdgcn_mfma_f32_16x16x32_bf16(
                    af[i], bfv[j], acc[i][j], 0, 0, 0);
    }
    const int fm4 = quad * 4;
    #pragma unroll
    for (int i = 0; i < 4; ++i) {
        int m = m0 + wr * 64 + i * 16 + fm4;
        if (m >= 2000) continue;
        #pragma unroll
        for (int j = 0; j < 4; ++j) {
            int d = wc * 64 + j * 16 + fm;
            f32x4 v = acc[i][j];
            bf16 pk[4] = {(bf16)v[0], (bf16)v[1], (bf16)v[2], (bf16)v[3]};
            *(uint2*)(Out + (size_t)s * sOut + (size_t)(b * 128 + d) * 2048 + m) = *(uint2*)pk;
        }
    }
}

// ---------------- bf16 MFMA GEMM: contract over nodes k ----------------
// A [2000][2016] bf16 per s (wavelet), Bt [1024][2048] bf16 per s (activation, trans).
// mode 0: trans-store [n][2048] with *rowscale[m]; mode 1: normal-store [m][1024] leaky.
__global__ __launch_bounds__(256) void hgemm_bf16(
    const bf16* __restrict__ A, long sA,
    const bf16* __restrict__ Bt, long sB,
    bf16* __restrict__ C, long sC,
    const float* __restrict__ rowscale, int mode)
{
    __shared__ bf16 As[128 * 32];
    __shared__ bf16 Bs[128 * 32];
    const int tid = threadIdx.x;
    const int lane = tid & 63, wave = tid >> 6;
    const int m0 = blockIdx.x * 128, n0 = blockIdx.y * 128;
    const int s = blockIdx.z;
    const bf16* Abase = A + (size_t)s * sA;
    const bf16* Bbase = Bt + (size_t)s * sB;
    const int wr = wave >> 1, wc = wave & 1;
    const int fm = lane & 15, quad = lane >> 4;

    const int c0 = wave * 128 + lane, c1 = c0 + 64;
    int rA0 = m0 + (c0 >> 2); if (rA0 > 1999) rA0 = 1999;
    int rA1 = m0 + (c1 >> 2); if (rA1 > 1999) rA1 = 1999;
    const bf16* a0p = Abase + (size_t)rA0 * 2016 + (c0 & 3) * 8;
    const bf16* a1p = Abase + (size_t)rA1 * 2016 + (c1 & 3) * 8;
    const bf16* b0p = Bbase + (size_t)(n0 + (c0 >> 2)) * 2048 + (c0 & 3) * 8;
    const bf16* b1p = Bbase + (size_t)(n0 + (c1 >> 2)) * 2048 + (c1 & 3) * 8;
    bf16* as0 = As + c0 * 8; bf16* as1 = As + c1 * 8;
    bf16* bs0 = Bs + c0 * 8; bf16* bs1 = Bs + c1 * 8;

    f32x4 acc[4][4] = {};
    for (int kt = 0; kt < 63; ++kt) {
        const int k0 = kt * 32;
        __builtin_amdgcn_global_load_lds((const GAS unsigned int*)(a0p + k0),
                                         (LAS unsigned int*)as0, 16, 0, 0);
        __builtin_amdgcn_global_load_lds((const GAS unsigned int*)(a1p + k0),
                                         (LAS unsigned int*)as1, 16, 0, 0);
        __builtin_amdgcn_global_load_lds((const GAS unsigned int*)(b0p + k0),
                                         (LAS unsigned int*)bs0, 16, 0, 0);
        __builtin_amdgcn_global_load_lds((const GAS unsigned int*)(b1p + k0),
                                         (LAS unsigned int*)bs1, 16, 0, 0);
        __syncthreads();
        bf16x8 af[4], bfv[4];
        #pragma unroll
        for (int i = 0; i < 4; ++i)
            af[i] = *(const bf16x8*)(As + (wr * 64 + i * 16 + fm) * 32 + quad * 8);
        #pragma unroll
        for (int j = 0; j < 4; ++j)
            bfv[j] = *(const bf16x8*)(Bs + (wc * 64 + j * 16 + fm) * 32 + quad * 8);
        #pragma unroll
        for (int i = 0; i < 4; ++i)
            #pragma unroll
            for (int j = 0; j < 4; ++j)
                acc[i][j] = __builtin_amdgcn_mfma_f32_16x16x32_bf16(
                    af[i], bfv[j], acc[i][j], 0, 0, 0);
        __syncthreads();
    }

    const int fm4 = quad * 4;
    if (mode == 0) {
        #pragma unroll
        for (int i = 0; i < 4; ++i) {
            int m = m0 + wr * 64 + i * 16 + fm4;
            if (m >= 2000) continue;
            #pragma unroll
            for (int j = 0; j < 4; ++j) {
                int n = n0 + wc * 64 + j * 16 + fm;
                f32x4 v = acc[i][j];
                float4 rs = *(const float4*)(rowscale + m);
                v[0] *= rs.x; v[1] *= rs.y; v[2] *= rs.z; v[3] *= rs.w;
                bf16 pk[4] = {(bf16)v[0], (bf16)v[1], (bf16)v[2], (bf16)v[3]};
                *(uint2*)(C + (size_t)s * sC + (size_t)n * 2048 + m) = *(uint2*)pk;
            }
        }
    } else {
        #pragma unroll
        for (int i = 0; i < 4; ++i) {
            int mb_ = m0 + wr * 64 + i * 16 + fm4;
            #pragma unroll
            for (int j = 0; j < 4; ++j) {
                int n = n0 + wc * 64 + j * 16 + fm;
                #pragma unroll
                for (int r = 0; r < 4; ++r) {
                    int m = mb_ + r;
                    if (m < 2000) {
                        float x = acc[i][j][r];
                        x = x > 0.f ? x : 0.1f * x;
                        C[(size_t)s * sC + (size_t)m * 1024 + n] = (bf16)x;
                    }
                }
            }
        }
    }
}

// ---------------- final MLP (fuses par-weighted sum over s) ----------------
__global__ __launch_bounds__(256) void mlp_kernel(
    const float* __restrict__ Xf, const bf16* __restrict__ F2,
    const float* __restrict__ par, const float* __restrict__ W1m,
    const float* __restrict__ b1m, const float* __restrict__ W2m,
    const float* __restrict__ b2m, float* __restrict__ out)
{
    __shared__ float w1s[256], b1s[16], w2s[16];
    int tid = threadIdx.x;
    w1s[tid] = W1m[tid];
    if (tid < 16) { b1s[tid] = b1m[tid]; w2s[tid] = W2m[tid]; }
    __syncthreads();
    int g = blockIdx.x * 256 + tid;           // 256000
    int t = g & 15;
    int r = g >> 4;
    int b = r / Nn, n = r % Nn;
    size_t base = (size_t)n * 1024 + b * 128 + t * 8;
    float p0 = par[0], p1 = par[1], p2 = par[2], p3 = par[3];
    float c[16];
    #pragma unroll
    for (int j = 0; j < 8; ++j) {
        c[j] = Xf[base + j];
        c[8 + j] = p0 * (float)F2[base + j]
                 + p1 * (float)F2[2097152 + base + j]
                 + p2 * (float)F2[4194304 + base + j]
                 + p3 * (float)F2[6291456 + base + j];
    }
    float acc = b2m[0];
    #pragma unroll
    for (int hh = 0; hh < 16; ++hh) {
        float hs = b1s[hh];
        #pragma unroll
        for (int cc = 0; cc < 16; ++cc) hs += c[cc] * w1s[cc * 16 + hh];
        acc += fmaxf(hs, 0.f) * w2s[hh];
    }
    out[g] = acc;
}

extern "C" void kernel_launch(void* const* d_in, const int* in_sizes, int n_in,
                              void* d_out, int out_size, void* d_ws, size_t ws_size,
                              hipStream_t stream)
{
    const float* inputs = (const float*)d_in[0];
    const float* emb_W  = (const float*)d_in[1];
    const float* emb_b  = (const float*)d_in[2];
    const float* W1     = (const float*)d_in[3];
    const float* U1     = (const float*)d_in[4];
    const float* b1     = (const float*)d_in[5];
    const float* ln1_g  = (const float*)d_in[6];
    const float* ln1_b  = (const float*)d_in[7];
    const float* W2     = (const float*)d_in[8];
    const float* U2     = (const float*)d_in[9];
    const float* b2     = (const float*)d_in[10];
    const float* Wq     = (const float*)d_in[11];
    const float* Wk     = (const float*)d_in[12];
    const float* Wv     = (const float*)d_in[13];
    const float* Wo     = (const float*)d_in[14];
    const float* ln2_g  = (const float*)d_in[15];
    const float* ln2_b  = (const float*)d_in[16];
    const float* par    = (const float*)d_in[17];
    const float* theta1 = (const float*)d_in[18];
    const float* diag1  = (const float*)d_in[19];
    const float* theta2 = (const float*)d_in[20];
    const float* diag2  = (const float*)d_in[21];
    const float* mlp1_W = (const float*)d_in[22];
    const float* mlp1_b = (const float*)d_in[23];
    const float* mlp2_W = (const float*)d_in[24];
    const float* mlp2_b = (const float*)d_in[25];
    const float* wav    = (const float*)d_in[26];
    const float* winv   = (const float*)d_in[27];
    float* ws  = (float*)d_ws;
    float* out = (float*)d_out;

    // ---- workspace layout (float offsets) ----
    float* xemb   = ws + 0;          // stage A
    float* h1     = ws + 4096000;
    float* o1     = ws + 0;          // aliases xemb
    float* h2     = ws + 8192000;
    float* enc    = ws + 10240000;
    float* qpart  = ws + 12288000;
    float* qb     = ws + 12681216;
    float* kb     = ws + 12685312;
    float* vb     = ws + 12689408;
    float* ctx    = ws + 12693504;
    float* resid2 = ws + 4096000;    // aliases h1
    float* Xf     = ws + 16128000;   // fp32 [2000][1024], live to end
    bf16*  Xfb    = (bf16*)(ws + 18176000);  // [2048][1024] node-major bf16
    bf16*  wavb   = (bf16*)(ws + 0);         // [4][2000][2016] (after ln2)
    bf16*  winvb  = (bf16*)(ws + 8064000);
    bf16*  X1b    = (bf16*)(ws + 19224576);  // [1024][2048] trans
    bf16*  Gb     = (bf16*)(ws + 20273152);  // [4][1024][2048] trans
    bf16*  Fb     = (bf16*)(ws + 24467456);  // [4][2048][1024] node-major
    bf16*  X2b    = (bf16*)(ws + 28661760);  // [4][1024][2048] trans
    bf16*  F2b    = (bf16*)(ws + 24467456);  // [4][2048][1024] aliases Fb
    bf16*  th1T   = (bf16*)(ws + 32856064);  // [128][128]
    bf16*  th2T   = (bf16*)(ws + 32864256);  // [128][128]

    // ---- stage A ----
    embed_kernel<<<16000, 256, 0, stream>>>(inputs, emb_W, emb_b, xemb);
    lstm1_kernel<<<4000, 256, 0, stream>>>(xemb, W1, U1, b1, h1);
    ln1_kernel<<<128, 1024, 0, stream>>>(h1, ln1_g, ln1_b, o1);
    lstm2_kernel<<<2000, 256, 0, stream>>>(o1, W2, U2, b2, h2);
    transp_kernel<<<8000, 256, 0, stream>>>(h2, enc);
    qkv_part_kernel<<<dim3(32, 8), 192, 0, stream>>>(enc, Wq, Wk, Wv, qpart);
    qkv_red_kernel<<<48, 256, 0, stream>>>(qpart, qb, kb, vb);
    attn_kernel<<<32, 256, 0, stream>>>(qb, kb, vb, ctx);
    ctxwo_kernel<<<dim3(63, 128), 256, 0, stream>>>(ctx, Wo, resid2);
    ln2_kernel<<<128, 1024, 0, stream>>>(enc, resid2, ln2_g, ln2_b, Xf, Xfb);

    // ---- stage B: conversions + padding ----
    cvt_pad_kernel<<<8000, 256, 0, stream>>>(wav, wavb);
    cvt_pad_kernel<<<8000, 256, 0, stream>>>(winv, winvb);
    thcvt_kernel<<<64, 256, 0, stream>>>(theta1, theta2, th1T, th2T);
    zero_pad_kernel<<<9216, 64, 0, stream>>>(X1b, Gb, X2b);

    // ---- hypergraph wavelet block ----
    const long sW = 4032000;     // wavelet slab stride (bf16)
    const long sAct = 2097152;   // [1024][2048] / [2048][1024] bf16
    theta_mfma<<<dim3(16, 8, 1), 256, 0, stream>>>(Xfb, 0, th1T, X1b, 0);
    hgemm_bf16<<<dim3(16, 8, 4), 256, 0, stream>>>(winvb, sW, X1b, 0, Gb, sAct, diag1, 0);
    hgemm_bf16<<<dim3(16, 8, 4), 256, 0, stream>>>(wavb, sW, Gb, sAct, Fb, sAct, nullptr, 1);
    theta_mfma<<<dim3(16, 8, 4), 256, 0, stream>>>(Fb, sAct, th2T, X2b, sAct);
    hgemm_bf16<<<dim3(16, 8, 4), 256, 0, stream>>>(winvb, sW, X2b, sAct, Gb, sAct, diag2, 0);
    hgemm_bf16<<<dim3(16, 8, 4), 256, 0, stream>>>(wavb, sW, Gb, sAct, F2b, sAct, nullptr, 1);

    // ---- head ----
    mlp_kernel<<<1000, 256, 0, stream>>>(Xf, F2b, par, mlp1_W, mlp1_b,
                                         mlp2_W, mlp2_b, out);
}

// Round 6
// 701.495 us; speedup vs baseline: 10.5400x; 1.0429x over previous
//
#include <hip/hip_runtime.h>
#include <cstddef>

#define Ss 4
#define Nn 2000
#define Tt 16
#define Ee 16
#define H1 16
#define H2 8
#define DMm 16000

typedef __bf16 bf16;
typedef bf16 bf16x8 __attribute__((ext_vector_type(8)));
typedef float f32x4 __attribute__((ext_vector_type(4)));
#define GAS __attribute__((address_space(1)))
#define LAS __attribute__((address_space(3)))

// ---------------- fold embed into LSTM1 x-path: Wf = emb_W@W1, bf = emb_b@W1 + b1 ----------------
__global__ __launch_bounds__(704) void wf_kernel(
    const float* __restrict__ eW, const float* __restrict__ eb,
    const float* __restrict__ W1, const float* __restrict__ b1,
    float* __restrict__ Wf, float* __restrict__ bfv)
{
    int tid = threadIdx.x;
    if (tid < 640) {
        int f = tid >> 6, g = tid & 63;
        float a = 0.f;
        #pragma unroll
        for (int e = 0; e < 16; ++e) a += eW[f * 16 + e] * W1[e * 64 + g];
        Wf[f * 64 + g] = a;
    } else if (tid < 704) {
        int g = tid - 640;
        float a = b1[g];
        #pragma unroll
        for (int e = 0; e < 16; ++e) a += eb[e] * W1[e * 64 + g];
        bfv[g] = a;
    }
}

// ---------------- Zx1[row][64] = inputs[row][10] @ Wf + bf ----------------
__global__ __launch_bounds__(256) void zx1_kernel(
    const float* __restrict__ in, const float* __restrict__ Wf,
    const float* __restrict__ bfv, float* __restrict__ Zx)
{
    int gidx = blockIdx.x * 256 + threadIdx.x;   // 16,384,000
    int g = gidx & 63;
    int row = gidx >> 6;
    const float* ip = in + (size_t)row * 10;
    float a = bfv[g];
    #pragma unroll
    for (int f = 0; f < 10; ++f) a += ip[f] * Wf[f * 64 + g];
    Zx[gidx] = a;
}

// ---------------- Zx2[row][32] = o1[row][16] @ W2 + b2 ----------------
__global__ __launch_bounds__(256) void zx2_kernel(
    const float* __restrict__ o1, const float* __restrict__ W2,
    const float* __restrict__ b2, float* __restrict__ Zx2)
{
    int gidx = blockIdx.x * 256 + threadIdx.x;   // 8,192,000
    int g = gidx & 31;
    int row = gidx >> 5;
    const float* op = o1 + (size_t)row * 16;
    float a = b2[g];
    #pragma unroll
    for (int e = 0; e < 16; ++e) a += op[e] * W2[e * 32 + g];
    Zx2[gidx] = a;
}

__device__ __forceinline__ float sigm(float x) { return 1.f / (1.f + __expf(-x)); }
__device__ __forceinline__ float tanh_f(float x) { return 2.f / (1.f + __expf(-2.f * x)) - 1.f; }

// ---------------- LSTM1 recurrence: 4 pairs/wave, lane = pl*16+j owns hidden j (4 gates) ----------------
__global__ __launch_bounds__(256) void lstm1_kernel(
    const float* __restrict__ Zx, const float* __restrict__ U1,
    float* __restrict__ h1)
{
    int tid = threadIdx.x;
    int lane = tid & 63, wid = tid >> 6;
    int pl = lane >> 4, j = lane & 15;
    int p = blockIdx.x * 16 + wid * 4 + pl;       // 16000 pairs
    float u[16][4];
    #pragma unroll
    for (int k = 0; k < 16; ++k)
        #pragma unroll
        for (int q = 0; q < 4; ++q)
            u[k][q] = U1[k * 64 + q * 16 + j];
    float hv = 0.f, cv = 0.f;
    const float* zp = Zx + (size_t)p * (16 * 64);
    float* hp = h1 + (size_t)p * (16 * 16);
    for (int t = 0; t < 16; ++t) {
        float zi = zp[t * 64 + j];
        float zf = zp[t * 64 + 16 + j];
        float zg = zp[t * 64 + 32 + j];
        float zo = zp[t * 64 + 48 + j];
        // broadcast h_k within this pair's 16-lane group: src = (lane & 0x10) | k (32-lane groups)
        #define LSTM1_STEP(k)                                                        \
        {                                                                            \
            float hk = __int_as_float(__builtin_amdgcn_ds_swizzle(                   \
                __float_as_int(hv), ((k) << 5) | 0x10));                             \
            zi += hk * u[k][0]; zf += hk * u[k][1];                                  \
            zg += hk * u[k][2]; zo += hk * u[k][3];                                  \
        }
        LSTM1_STEP(0) LSTM1_STEP(1) LSTM1_STEP(2) LSTM1_STEP(3)
        LSTM1_STEP(4) LSTM1_STEP(5) LSTM1_STEP(6) LSTM1_STEP(7)
        LSTM1_STEP(8) LSTM1_STEP(9) LSTM1_STEP(10) LSTM1_STEP(11)
        LSTM1_STEP(12) LSTM1_STEP(13) LSTM1_STEP(14) LSTM1_STEP(15)
        #undef LSTM1_STEP
        float ig = sigm(zi), fg = sigm(zf), og = sigm(zo);
        cv = fg * cv + ig * tanh_f(zg);
        hv = og * tanh_f(cv);
        hp[t * 16 + j] = hv;
    }
}

// ---------------- LSTM2 recurrence: 8 pairs/wave, lane = pg*8+j ----------------
__global__ __launch_bounds__(256) void lstm2_kernel(
    const float* __restrict__ Zx2, const float* __restrict__ U2,
    float* __restrict__ h2)
{
    int tid = threadIdx.x;
    int lane = tid & 63, wid = tid >> 6;
    int pg = lane >> 3, j = lane & 7;
    int p = blockIdx.x * 32 + wid * 8 + pg;       // 16000 pairs
    float u[8][4];
    #pragma unroll
    for (int k = 0; k < 8; ++k)
        #pragma unroll
        for (int q = 0; q < 4; ++q)
            u[k][q] = U2[k * 32 + q * 8 + j];
    float hv = 0.f, cv = 0.f;
    const float* zp = Zx2 + (size_t)p * (16 * 32);
    float* hp = h2 + (size_t)p * (16 * 8);
    for (int t = 0; t < 16; ++t) {
        float zi = zp[t * 32 + j];
        float zf = zp[t * 32 + 8 + j];
        float zg = zp[t * 32 + 16 + j];
        float zo = zp[t * 32 + 24 + j];
        // broadcast h_k within this pair's 8-lane group: src = (lane & 0x18) | k
        #define LSTM2_STEP(k)                                                        \
        {                                                                            \
            float hk = __int_as_float(__builtin_amdgcn_ds_swizzle(                   \
                __float_as_int(hv), ((k) << 5) | 0x18));                             \
            zi += hk * u[k][0]; zf += hk * u[k][1];                                  \
            zg += hk * u[k][2]; zo += hk * u[k][3];                                  \
        }
        LSTM2_STEP(0) LSTM2_STEP(1) LSTM2_STEP(2) LSTM2_STEP(3)
        LSTM2_STEP(4) LSTM2_STEP(5) LSTM2_STEP(6) LSTM2_STEP(7)
        #undef LSTM2_STEP
        float ig = sigm(zi), fg = sigm(zf), og = sigm(zo);
        cv = fg * cv + ig * tanh_f(zg);
        hv = og * tanh_f(cv);
        hp[t * 8 + j] = hv;
    }
}

template<int NW>
__device__ __forceinline__ void block_reduce2t(float& a, float& b)
{
    #pragma unroll
    for (int off = 32; off; off >>= 1) {
        a += __shfl_xor(a, off);
        b += __shfl_xor(b, off);
    }
    __shared__ float r[2 * NW];
    int tid = threadIdx.x;
    if ((tid & 63) == 0) { r[tid >> 6] = a; r[NW + (tid >> 6)] = b; }
    __syncthreads();
    a = 0.f; b = 0.f;
    #pragma unroll
    for (int w = 0; w < NW; ++w) { a += r[w]; b += r[NW + w]; }
}

// ---------------- LN1 ----------------
__global__ __launch_bounds__(1024) void ln1_kernel(
    const float* __restrict__ h1, const float* __restrict__ g,
    const float* __restrict__ bta, float* __restrict__ o1)
{
    int b = blockIdx.x >> 4, t = blockIdx.x & 15;
    int tid = threadIdx.x;
    float sum = 0.f, sq = 0.f;
    for (int i = tid; i < Nn * H1; i += 1024) {
        int n = i >> 4, j = i & 15;
        float v = h1[(((size_t)b * Nn + n) * Tt + t) * H1 + j];
        sum += v; sq += v * v;
    }
    block_reduce2t<16>(sum, sq);
    float mu = sum * (1.f / (Nn * H1));
    float var = sq * (1.f / (Nn * H1)) - mu * mu;
    float rstd = rsqrtf(var + 1e-5f);
    for (int i = tid; i < Nn * H1; i += 1024) {
        int n = i >> 4, j = i & 15;
        size_t idx = (((size_t)b * Nn + n) * Tt + t) * H1 + j;
        o1[idx] = (h1[idx] - mu) * rstd * g[i] + bta[i];
    }
}

// ---------------- transpose h2 -> enc [B*T][16000] ----------------
__global__ __launch_bounds__(256) void transp_kernel(
    const float* __restrict__ h2, float* __restrict__ enc)
{
    int g = blockIdx.x * 256 + threadIdx.x;   // 2,048,000
    int r = g & 127;
    int p = g >> 7;
    int b = p / Nn, n = p % Nn;
    enc[(size_t)(b * 16 + (r >> 3)) * DMm + n * 8 + (r & 7)] = h2[g];
}

// ---------------- QKV split-K partials ----------------
__global__ __launch_bounds__(192) void qkv_part_kernel(
    const float* __restrict__ enc, const float* __restrict__ Wq,
    const float* __restrict__ Wk, const float* __restrict__ Wv,
    float* __restrict__ partial)
{
    __shared__ float encT[500 * 16];
    int ks = blockIdx.x, btg = blockIdx.y;
    int tid = threadIdx.x;
    int k0 = ks * 500;
    for (int idx = tid; idx < 8000; idx += 192) {
        int kk = idx >> 4, r = idx & 15;
        encT[idx] = enc[(size_t)(btg * 16 + r) * DMm + k0 + kk];
    }
    __syncthreads();
    int c = tid % 96, rg = tid / 96;
    int cc = c & 31;
    const float* W = (c < 32) ? Wq : ((c < 64) ? Wk : Wv);
    float acc[8] = {};
    for (int kk = 0; kk < 500; ++kk) {
        float w = W[(size_t)(k0 + kk) * 32 + cc];
        const float* e = &encT[kk * 16 + rg * 8];
        #pragma unroll
        for (int r8 = 0; r8 < 8; ++r8) acc[r8] += e[r8] * w;
    }
    #pragma unroll
    for (int r8 = 0; r8 < 8; ++r8)
        partial[((size_t)ks * 128 + btg * 16 + rg * 8 + r8) * 96 + c] = acc[r8];
}

// ---------------- QKV reduce ----------------
__global__ __launch_bounds__(256) void qkv_red_kernel(
    const float* __restrict__ partial, float* __restrict__ qb,
    float* __restrict__ kb, float* __restrict__ vb)
{
    int o = blockIdx.x * 256 + threadIdx.x;   // 12288
    int bt = o / 96, c = o % 96;
    float v = 0.f;
    for (int ks = 0; ks < 32; ++ks) v += partial[(size_t)ks * 12288 + o];
    int b = bt >> 4, t = bt & 15;
    int cc = c & 31, h = cc >> 3, dk = cc & 7;
    float* dst = (c < 32) ? qb : ((c < 64) ? kb : vb);
    dst[(((size_t)b * 4 + h) * 16 + t) * 8 + dk] = v;
}

// ---------------- attention ----------------
__global__ __launch_bounds__(256) void attn_kernel(
    const float* __restrict__ qb, const float* __restrict__ kb,
    const float* __restrict__ vb, float* __restrict__ ctx)
{
    int bh = blockIdx.x;
    int b = bh >> 2, h = bh & 3;
    __shared__ float qs[128], ks[128], vs[128], att[16][16];
    int tid = threadIdx.x;
    if (tid < 128) {
        qs[tid] = qb[(size_t)bh * 128 + tid];
        ks[tid] = kb[(size_t)bh * 128 + tid];
        vs[tid] = vb[(size_t)bh * 128 + tid];
    }
    __syncthreads();
    int qt = tid >> 4, kt = tid & 15;
    float s = -1e9f;
    if (kt <= qt) {
        float d = 0.f;
        #pragma unroll
        for (int x = 0; x < 8; ++x) d += qs[qt * 8 + x] * ks[kt * 8 + x];
        s = d * 0.35355339059327373f;
    }
    float mx = s;
    #pragma unroll
    for (int off = 8; off; off >>= 1) mx = fmaxf(mx, __shfl_xor(mx, off, 16));
    float p = __expf(s - mx);
    float sm = p;
    #pragma unroll
    for (int off = 8; off; off >>= 1) sm += __shfl_xor(sm, off, 16);
    att[qt][kt] = p / sm;
    __syncthreads();
    if (tid < 128) {
        int q2 = tid >> 3, dv = tid & 7;
        float cacc = 0.f;
        #pragma unroll
        for (int k2 = 0; k2 < 16; ++k2) cacc += att[q2][k2] * vs[k2 * 8 + dv];
        ctx[((size_t)b * 16 + q2) * 32 + h * 8 + dv] = cacc;
    }
}

// ---------------- ctx @ Wo -> resid2 [BT][16000] ----------------
__global__ __launch_bounds__(256) void ctxwo_kernel(
    const float* __restrict__ ctx, const float* __restrict__ Wo,
    float* __restrict__ resid2)
{
    int bt = blockIdx.y;
    int m = blockIdx.x * 256 + threadIdx.x;
    __shared__ float cs[32];
    if (threadIdx.x < 32) cs[threadIdx.x] = ctx[(size_t)bt * 32 + threadIdx.x];
    __syncthreads();
    if (m < DMm) {
        float acc = 0.f;
        #pragma unroll
        for (int j = 0; j < 32; ++j) acc += cs[j] * Wo[(size_t)j * DMm + m];
        resid2[(size_t)bt * DMm + m] = acc;
    }
}

// ---------------- LN2: writes Xf fp32 [2000][1024] and Xfb bf16 [2048][1024] ----------------
__global__ __launch_bounds__(1024) void ln2_kernel(
    const float* __restrict__ enc, float* __restrict__ resid2,
    const float* __restrict__ g2, const float* __restrict__ b2v,
    float* __restrict__ Xf, bf16* __restrict__ Xfb)
{
    int bt = blockIdx.x;
    int b = bt >> 4, t = bt & 15;
    int tid = threadIdx.x;
    float sum = 0.f, sq = 0.f;
    for (int m = tid; m < DMm; m += 1024) {
        float v = enc[(size_t)bt * DMm + m] + resid2[(size_t)bt * DMm + m];
        resid2[(size_t)bt * DMm + m] = v;
        sum += v; sq += v * v;
    }
    block_reduce2t<16>(sum, sq);
    float mu = sum * (1.f / DMm);
    float var = sq * (1.f / DMm) - mu * mu;
    float rstd = rsqrtf(var + 1e-5f);
    for (int m = tid; m < DMm; m += 1024) {
        float v = resid2[(size_t)bt * DMm + m];
        float y = (v - mu) * rstd * g2[m] + b2v[m];
        int n = m >> 3, j = m & 7;
        size_t o = (size_t)n * 1024 + b * 128 + t * 8 + j;
        Xf[o] = y;
        Xfb[o] = (bf16)y;
    }
}

// ---------------- fp32 -> bf16 with k-pad to 2016, vectorized ----------------
__global__ __launch_bounds__(256) void cvt_pad_kernel(
    const float* __restrict__ src, bf16* __restrict__ dst)
{
    int row = blockIdx.x;                     // 8000 rows (4 s * 2000)
    int tid = threadIdx.x;
    if (tid >= 252) return;
    int col = tid * 8;
    bf16 pk[8];
    if (col < 2000) {
        float4 v0 = *(const float4*)(src + (size_t)row * 2000 + col);
        float4 v1 = *(const float4*)(src + (size_t)row * 2000 + col + 4);
        pk[0] = (bf16)v0.x; pk[1] = (bf16)v0.y; pk[2] = (bf16)v0.z; pk[3] = (bf16)v0.w;
        pk[4] = (bf16)v1.x; pk[5] = (bf16)v1.y; pk[6] = (bf16)v1.z; pk[7] = (bf16)v1.w;
    } else {
        #pragma unroll
        for (int i = 0; i < 8; ++i) pk[i] = (bf16)0.f;
    }
    *(uint4*)(dst + (size_t)row * 2016 + col) = *(uint4*)pk;
}

// ---------------- zero pad cols [2000,2048) of trans-layout activation buffers ----------------
__global__ __launch_bounds__(64) void zero_pad_kernel(
    bf16* __restrict__ X1b, bf16* __restrict__ Gb, bf16* __restrict__ X2b)
{
    int row = blockIdx.x;                     // 9216 rows total
    int tid = threadIdx.x;
    if (tid >= 48) return;
    bf16* p;
    if (row < 1024) p = X1b + (size_t)row * 2048;
    else if (row < 5120) p = Gb + (size_t)(row - 1024) * 2048;
    else p = X2b + (size_t)(row - 5120) * 2048;
    p[2000 + tid] = (bf16)0.f;
}

// ---------------- theta transpose+cast ----------------
__global__ __launch_bounds__(256) void thcvt_kernel(
    const float* __restrict__ th1, const float* __restrict__ th2,
    bf16* __restrict__ th1T, bf16* __restrict__ th2T)
{
    int g = blockIdx.x * 256 + threadIdx.x;   // 16384
    int d = g >> 7, d0 = g & 127;
    th1T[g] = (bf16)th1[(size_t)d0 * 128 + d];
    th2T[g] = (bf16)th2[(size_t)d0 * 128 + d];
}

// ---------------- theta MFMA ----------------
__global__ __launch_bounds__(256) void theta_mfma(
    const bf16* __restrict__ Act, long sAct, const bf16* __restrict__ thT,
    bf16* __restrict__ Out, long sOut)
{
    __shared__ bf16 As2[128 * 128];
    __shared__ bf16 Bs2[128 * 128];
    const int tid = threadIdx.x;
    const int lane = tid & 63, wave = tid >> 6;
    const int m0 = blockIdx.x * 128, b = blockIdx.y, s = blockIdx.z;
    const bf16* Ab = Act + (size_t)s * sAct + (size_t)m0 * 1024 + b * 128;
    #pragma unroll
    for (int r = 0; r < 8; ++r) {
        int c = r * 256 + wave * 64 + lane;   // 0..2047
        int row = c >> 4, col8 = (c & 15) * 8;
        __builtin_amdgcn_global_load_lds(
            (const GAS unsigned int*)(Ab + (size_t)row * 1024 + col8),
            (LAS unsigned int*)(As2 + c * 8), 16, 0, 0);
        __builtin_amdgcn_global_load_lds(
            (const GAS unsigned int*)(thT + (size_t)row * 128 + col8),
            (LAS unsigned int*)(Bs2 + c * 8), 16, 0, 0);
    }
    __syncthreads();
    const int wr = wave >> 1, wc = wave & 1;
    const int fm = lane & 15, quad = lane >> 4;
    f32x4 acc[4][4] = {};
    #pragma unroll
    for (int ks = 0; ks < 4; ++ks) {
        bf16x8 af[4], bfv[4];
        #pragma unroll
        for (int i = 0; i < 4; ++i)
            af[i] = *(const bf16x8*)(As2 + (wr * 64 + i * 16 + fm) * 128 + ks * 32 + quad * 8);
        #pragma unroll
        for (int j = 0; j < 4; ++j)
            bfv[j] = *(const bf16x8*)(Bs2 + (wc * 64 + j * 16 + fm) * 128 + ks * 32 + quad * 8);
        #pragma unroll
        for (int i = 0; i < 4; ++i)
            #pragma unroll
            for (int j = 0; j < 4; ++j)
                acc[i][j] = __builtin_amdgcn_mfma_f32_16x16x32_bf16(
                    af[i], bfv[j], acc[i][j], 0, 0, 0);
    }
    const int fm4 = quad * 4;
    #pragma unroll
    for (int i = 0; i < 4; ++i) {
        int m = m0 + wr * 64 + i * 16 + fm4;
        if (m >= 2000) continue;
        #pragma unroll
        for (int j = 0; j < 4; ++j) {
            int d = wc * 64 + j * 16 + fm;
            f32x4 v = acc[i][j];
            bf16 pk[4] = {(bf16)v[0], (bf16)v[1], (bf16)v[2], (bf16)v[3]};
            *(uint2*)(Out + (size_t)s * sOut + (size_t)(b * 128 + d) * 2048 + m) = *(uint2*)pk;
        }
    }
}

// ---------------- bf16 MFMA GEMM ----------------
__global__ __launch_bounds__(256) void hgemm_bf16(
    const bf16* __restrict__ A, long sA,
    const bf16* __restrict__ Bt, long sB,
    bf16* __restrict__ C, long sC,
    const float* __restrict__ rowscale, int mode)
{
    __shared__ bf16 As[128 * 32];
    __shared__ bf16 Bs[128 * 32];
    const int tid = threadIdx.x;
    const int lane = tid & 63, wave = tid >> 6;
    const int m0 = blockIdx.x * 128, n0 = blockIdx.y * 128;
    const int s = blockIdx.z;
    const bf16* Abase = A + (size_t)s * sA;
    const bf16* Bbase = Bt + (size_t)s * sB;
    const int wr = wave >> 1, wc = wave & 1;
    const int fm = lane & 15, quad = lane >> 4;

    const int c0 = wave * 128 + lane, c1 = c0 + 64;
    int rA0 = m0 + (c0 >> 2); if (rA0 > 1999) rA0 = 1999;
    int rA1 = m0 + (c1 >> 2); if (rA1 > 1999) rA1 = 1999;
    const bf16* a0p = Abase + (size_t)rA0 * 2016 + (c0 & 3) * 8;
    const bf16* a1p = Abase + (size_t)rA1 * 2016 + (c1 & 3) * 8;
    const bf16* b0p = Bbase + (size_t)(n0 + (c0 >> 2)) * 2048 + (c0 & 3) * 8;
    const bf16* b1p = Bbase + (size_t)(n0 + (c1 >> 2)) * 2048 + (c1 & 3) * 8;
    bf16* as0 = As + c0 * 8; bf16* as1 = As + c1 * 8;
    bf16* bs0 = Bs + c0 * 8; bf16* bs1 = Bs + c1 * 8;

    f32x4 acc[4][4] = {};
    for (int kt = 0; kt < 63; ++kt) {
        const int k0 = kt * 32;
        __builtin_amdgcn_global_load_lds((const GAS unsigned int*)(a0p + k0),
                                         (LAS unsigned int*)as0, 16, 0, 0);
        __builtin_amdgcn_global_load_lds((const GAS unsigned int*)(a1p + k0),
                                         (LAS unsigned int*)as1, 16, 0, 0);
        __builtin_amdgcn_global_load_lds((const GAS unsigned int*)(b0p + k0),
                                         (LAS unsigned int*)bs0, 16, 0, 0);
        __builtin_amdgcn_global_load_lds((const GAS unsigned int*)(b1p + k0),
                                         (LAS unsigned int*)bs1, 16, 0, 0);
        __syncthreads();
        bf16x8 af[4], bfv[4];
        #pragma unroll
        for (int i = 0; i < 4; ++i)
            af[i] = *(const bf16x8*)(As + (wr * 64 + i * 16 + fm) * 32 + quad * 8);
        #pragma unroll
        for (int j = 0; j < 4; ++j)
            bfv[j] = *(const bf16x8*)(Bs + (wc * 64 + j * 16 + fm) * 32 + quad * 8);
        #pragma unroll
        for (int i = 0; i < 4; ++i)
            #pragma unroll
            for (int j = 0; j < 4; ++j)
                acc[i][j] = __builtin_amdgcn_mfma_f32_16x16x32_bf16(
                    af[i], bfv[j], acc[i][j], 0, 0, 0);
        __syncthreads();
    }

    const int fm4 = quad * 4;
    if (mode == 0) {
        #pragma unroll
        for (int i = 0; i < 4; ++i) {
            int m = m0 + wr * 64 + i * 16 + fm4;
            if (m >= 2000) continue;
            #pragma unroll
            for (int j = 0; j < 4; ++j) {
                int n = n0 + wc * 64 + j * 16 + fm;
                f32x4 v = acc[i][j];
                float4 rs = *(const float4*)(rowscale + m);
                v[0] *= rs.x; v[1] *= rs.y; v[2] *= rs.z; v[3] *= rs.w;
                bf16 pk[4] = {(bf16)v[0], (bf16)v[1], (bf16)v[2], (bf16)v[3]};
                *(uint2*)(C + (size_t)s * sC + (size_t)n * 2048 + m) = *(uint2*)pk;
            }
        }
    } else {
        #pragma unroll
        for (int i = 0; i < 4; ++i) {
            int mb_ = m0 + wr * 64 + i * 16 + fm4;
            #pragma unroll
            for (int j = 0; j < 4; ++j) {
                int n = n0 + wc * 64 + j * 16 + fm;
                #pragma unroll
                for (int r = 0; r < 4; ++r) {
                    int m = mb_ + r;
                    if (m < 2000) {
                        float x = acc[i][j][r];
                        x = x > 0.f ? x : 0.1f * x;
                        C[(size_t)s * sC + (size_t)m * 1024 + n] = (bf16)x;
                    }
                }
            }
        }
    }
}

// ---------------- final MLP (fuses par-weighted sum over s) ----------------
__global__ __launch_bounds__(256) void mlp_kernel(
    const float* __restrict__ Xf, const bf16* __restrict__ F2,
    const float* __restrict__ par, const float* __restrict__ W1m,
    const float* __restrict__ b1m, const float* __restrict__ W2m,
    const float* __restrict__ b2m, float* __restrict__ out)
{
    __shared__ float w1s[256], b1s[16], w2s[16];
    int tid = threadIdx.x;
    w1s[tid] = W1m[tid];
    if (tid < 16) { b1s[tid] = b1m[tid]; w2s[tid] = W2m[tid]; }
    __syncthreads();
    int g = blockIdx.x * 256 + tid;           // 256000
    int t = g & 15;
    int r = g >> 4;
    int b = r / Nn, n = r % Nn;
    size_t base = (size_t)n * 1024 + b * 128 + t * 8;
    float p0 = par[0], p1 = par[1], p2 = par[2], p3 = par[3];
    float c[16];
    #pragma unroll
    for (int j = 0; j < 8; ++j) {
        c[j] = Xf[base + j];
        c[8 + j] = p0 * (float)F2[base + j]
                 + p1 * (float)F2[2097152 + base + j]
                 + p2 * (float)F2[4194304 + base + j]
                 + p3 * (float)F2[6291456 + base + j];
    }
    float acc = b2m[0];
    #pragma unroll
    for (int hh = 0; hh < 16; ++hh) {
        float hs = b1s[hh];
        #pragma unroll
        for (int cc = 0; cc < 16; ++cc) hs += c[cc] * w1s[cc * 16 + hh];
        acc += fmaxf(hs, 0.f) * w2s[hh];
    }
    out[g] = acc;
}

extern "C" void kernel_launch(void* const* d_in, const int* in_sizes, int n_in,
                              void* d_out, int out_size, void* d_ws, size_t ws_size,
                              hipStream_t stream)
{
    const float* inputs = (const float*)d_in[0];
    const float* emb_W  = (const float*)d_in[1];
    const float* emb_b  = (const float*)d_in[2];
    const float* W1     = (const float*)d_in[3];
    const float* U1     = (const float*)d_in[4];
    const float* b1     = (const float*)d_in[5];
    const float* ln1_g  = (const float*)d_in[6];
    const float* ln1_b  = (const float*)d_in[7];
    const float* W2     = (const float*)d_in[8];
    const float* U2     = (const float*)d_in[9];
    const float* b2     = (const float*)d_in[10];
    const float* Wq     = (const float*)d_in[11];
    const float* Wk     = (const float*)d_in[12];
    const float* Wv     = (const float*)d_in[13];
    const float* Wo     = (const float*)d_in[14];
    const float* ln2_g  = (const float*)d_in[15];
    const float* ln2_b  = (const float*)d_in[16];
    const float* par    = (const float*)d_in[17];
    const float* theta1 = (const float*)d_in[18];
    const float* diag1  = (const float*)d_in[19];
    const float* theta2 = (const float*)d_in[20];
    const float* diag2  = (const float*)d_in[21];
    const float* mlp1_W = (const float*)d_in[22];
    const float* mlp1_b = (const float*)d_in[23];
    const float* mlp2_W = (const float*)d_in[24];
    const float* mlp2_b = (const float*)d_in[25];
    const float* wav    = (const float*)d_in[26];
    const float* winv   = (const float*)d_in[27];
    float* ws  = (float*)d_ws;
    float* out = (float*)d_out;

    // ---- workspace layout (float offsets); peak unchanged vs r5 (32,872,448 fl) ----
    float* Zx1    = ws + 0;          // [0, 16,384,000)  dead after lstm1
    float* h1     = ws + 16384000;   // [16,384,000, 20,480,000) dead after ln1
    float* o1     = ws + 0;          // [0, 4,096,000)   dead after zx2
    float* Zx2    = ws + 4096000;    // [4,096,000, 12,288,000) dead after lstm2
    float* h2     = ws + 12288000;   // [12,288,000, 14,336,000) dead after transp
    float* enc    = ws + 10240000;   // [10,240,000, 12,288,000) dead after ln2
    float* qpart  = ws + 12288000;   // written after transp (h2 dead)
    float* qb     = ws + 12681216;
    float* kb     = ws + 12685312;
    float* vb     = ws + 12689408;
    float* ctx    = ws + 12693504;
    float* resid2 = ws + 4096000;    // written at ctxwo (Zx2 dead)
    float* Xf     = ws + 16128000;   // fp32 [2000][1024], live to end (h1 dead)
    bf16*  Xfb    = (bf16*)(ws + 18176000);  // [2048][1024] node-major bf16
    bf16*  wavb   = (bf16*)(ws + 0);         // [4][2000][2016] (after ln2)
    bf16*  winvb  = (bf16*)(ws + 8064000);
    bf16*  X1b    = (bf16*)(ws + 19224576);  // [1024][2048] trans
    bf16*  Gb     = (bf16*)(ws + 20273152);  // [4][1024][2048] trans
    bf16*  Fb     = (bf16*)(ws + 24467456);  // [4][2048][1024] node-major
    bf16*  X2b    = (bf16*)(ws + 28661760);  // [4][1024][2048] trans
    bf16*  F2b    = (bf16*)(ws + 24467456);  // aliases Fb
    bf16*  th1T   = (bf16*)(ws + 32856064);  // [128][128]
    bf16*  th2T   = (bf16*)(ws + 32864256);  // [128][128]
    float* Wf     = ws + 20480000;   // [10][64] fused embed*W1 (inside Gb region, dead before Gb)
    float* bfB    = ws + 20480640;   // [64]

    // ---- stage A ----
    wf_kernel<<<1, 704, 0, stream>>>(emb_W, emb_b, W1, b1, Wf, bfB);
    zx1_kernel<<<64000, 256, 0, stream>>>(inputs, Wf, bfB, Zx1);
    lstm1_kernel<<<1000, 256, 0, stream>>>(Zx1, U1, h1);
    ln1_kernel<<<128, 1024, 0, stream>>>(h1, ln1_g, ln1_b, o1);
    zx2_kernel<<<32000, 256, 0, stream>>>(o1, W2, b2, Zx2);
    lstm2_kernel<<<500, 256, 0, stream>>>(Zx2, U2, h2);
    transp_kernel<<<8000, 256, 0, stream>>>(h2, enc);
    qkv_part_kernel<<<dim3(32, 8), 192, 0, stream>>>(enc, Wq, Wk, Wv, qpart);
    qkv_red_kernel<<<48, 256, 0, stream>>>(qpart, qb, kb, vb);
    attn_kernel<<<32, 256, 0, stream>>>(qb, kb, vb, ctx);
    ctxwo_kernel<<<dim3(63, 128), 256, 0, stream>>>(ctx, Wo, resid2);
    ln2_kernel<<<128, 1024, 0, stream>>>(enc, resid2, ln2_g, ln2_b, Xf, Xfb);

    // ---- stage B: conversions + padding ----
    cvt_pad_kernel<<<8000, 256, 0, stream>>>(wav, wavb);
    cvt_pad_kernel<<<8000, 256, 0, stream>>>(winv, winvb);
    thcvt_kernel<<<64, 256, 0, stream>>>(theta1, theta2, th1T, th2T);
    zero_pad_kernel<<<9216, 64, 0, stream>>>(X1b, Gb, X2b);

    // ---- hypergraph wavelet block ----
    const long sW = 4032000;     // wavelet slab stride (bf16)
    const long sAct = 2097152;   // [1024][2048] / [2048][1024] bf16
    theta_mfma<<<dim3(16, 8, 1), 256, 0, stream>>>(Xfb, 0, th1T, X1b, 0);
    hgemm_bf16<<<dim3(16, 8, 4), 256, 0, stream>>>(winvb, sW, X1b, 0, Gb, sAct, diag1, 0);
    hgemm_bf16<<<dim3(16, 8, 4), 256, 0, stream>>>(wavb, sW, Gb, sAct, Fb, sAct, nullptr, 1);
    theta_mfma<<<dim3(16, 8, 4), 256, 0, stream>>>(Fb, sAct, th2T, X2b, sAct);
    hgemm_bf16<<<dim3(16, 8, 4), 256, 0, stream>>>(winvb, sW, X2b, sAct, Gb, sAct, diag2, 0);
    hgemm_bf16<<<dim3(16, 8, 4), 256, 0, stream>>>(wavb, sW, Gb, sAct, F2b, sAct, nullptr, 1);

    // ---- head ----
    mlp_kernel<<<1000, 256, 0, stream>>>(Xf, F2b, par, mlp1_W, mlp1_b,
                                         mlp2_W, mlp2_b, out);
}

// Round 7
// 663.654 us; speedup vs baseline: 11.1410x; 1.0570x over previous
//
#include <hip/hip_runtime.h>
#include <cstddef>

#define Ss 4
#define Nn 2000
#define Tt 16
#define Ee 16
#define H1 16
#define H2 8
#define DMm 16000

typedef __bf16 bf16;
typedef bf16 bf16x8 __attribute__((ext_vector_type(8)));
typedef float f32x4 __attribute__((ext_vector_type(4)));
#define GAS __attribute__((address_space(1)))
#define LAS __attribute__((address_space(3)))

// ---------------- fold embed into LSTM1 x-path: Wf = emb_W@W1, bf = emb_b@W1 + b1 ----------------
__global__ __launch_bounds__(704) void wf_kernel(
    const float* __restrict__ eW, const float* __restrict__ eb,
    const float* __restrict__ W1, const float* __restrict__ b1,
    float* __restrict__ Wf, float* __restrict__ bfv)
{
    int tid = threadIdx.x;
    if (tid < 640) {
        int f = tid >> 6, g = tid & 63;
        float a = 0.f;
        #pragma unroll
        for (int e = 0; e < 16; ++e) a += eW[f * 16 + e] * W1[e * 64 + g];
        Wf[f * 64 + g] = a;
    } else if (tid < 704) {
        int g = tid - 640;
        float a = b1[g];
        #pragma unroll
        for (int e = 0; e < 16; ++e) a += eb[e] * W1[e * 64 + g];
        bfv[g] = a;
    }
}

// ---------------- Zx1[row][64] = inputs[row][10] @ Wf + bf ----------------
__global__ __launch_bounds__(256) void zx1_kernel(
    const float* __restrict__ in, const float* __restrict__ Wf,
    const float* __restrict__ bfv, float* __restrict__ Zx)
{
    int gidx = blockIdx.x * 256 + threadIdx.x;   // 16,384,000
    int g = gidx & 63;
    int row = gidx >> 6;
    const float* ip = in + (size_t)row * 10;
    float a = bfv[g];
    #pragma unroll
    for (int f = 0; f < 10; ++f) a += ip[f] * Wf[f * 64 + g];
    Zx[gidx] = a;
}

// ---------------- Zx2[row][32] = o1[row][16] @ W2 + b2 ----------------
__global__ __launch_bounds__(256) void zx2_kernel(
    const float* __restrict__ o1, const float* __restrict__ W2,
    const float* __restrict__ b2, float* __restrict__ Zx2)
{
    int gidx = blockIdx.x * 256 + threadIdx.x;   // 8,192,000
    int g = gidx & 31;
    int row = gidx >> 5;
    const float* op = o1 + (size_t)row * 16;
    float a = b2[g];
    #pragma unroll
    for (int e = 0; e < 16; ++e) a += op[e] * W2[e * 32 + g];
    Zx2[gidx] = a;
}

__device__ __forceinline__ float sigm(float x) { return 1.f / (1.f + __expf(-x)); }
__device__ __forceinline__ float tanh_f(float x) { return 2.f / (1.f + __expf(-2.f * x)) - 1.f; }

// ---------------- LSTM1 recurrence: 4 pairs/wave ----------------
__global__ __launch_bounds__(256) void lstm1_kernel(
    const float* __restrict__ Zx, const float* __restrict__ U1,
    float* __restrict__ h1)
{
    int tid = threadIdx.x;
    int lane = tid & 63, wid = tid >> 6;
    int pl = lane >> 4, j = lane & 15;
    int p = blockIdx.x * 16 + wid * 4 + pl;       // 16000 pairs
    float u[16][4];
    #pragma unroll
    for (int k = 0; k < 16; ++k)
        #pragma unroll
        for (int q = 0; q < 4; ++q)
            u[k][q] = U1[k * 64 + q * 16 + j];
    float hv = 0.f, cv = 0.f;
    const float* zp = Zx + (size_t)p * (16 * 64);
    float* hp = h1 + (size_t)p * (16 * 16);
    for (int t = 0; t < 16; ++t) {
        float zi = zp[t * 64 + j];
        float zf = zp[t * 64 + 16 + j];
        float zg = zp[t * 64 + 32 + j];
        float zo = zp[t * 64 + 48 + j];
        #define LSTM1_STEP(k)                                                        \
        {                                                                            \
            float hk = __int_as_float(__builtin_amdgcn_ds_swizzle(                   \
                __float_as_int(hv), ((k) << 5) | 0x10));                             \
            zi += hk * u[k][0]; zf += hk * u[k][1];                                  \
            zg += hk * u[k][2]; zo += hk * u[k][3];                                  \
        }
        LSTM1_STEP(0) LSTM1_STEP(1) LSTM1_STEP(2) LSTM1_STEP(3)
        LSTM1_STEP(4) LSTM1_STEP(5) LSTM1_STEP(6) LSTM1_STEP(7)
        LSTM1_STEP(8) LSTM1_STEP(9) LSTM1_STEP(10) LSTM1_STEP(11)
        LSTM1_STEP(12) LSTM1_STEP(13) LSTM1_STEP(14) LSTM1_STEP(15)
        #undef LSTM1_STEP
        float ig = sigm(zi), fg = sigm(zf), og = sigm(zo);
        cv = fg * cv + ig * tanh_f(zg);
        hv = og * tanh_f(cv);
        hp[t * 16 + j] = hv;
    }
}

// ---------------- LSTM2 recurrence: 8 pairs/wave ----------------
__global__ __launch_bounds__(256) void lstm2_kernel(
    const float* __restrict__ Zx2, const float* __restrict__ U2,
    float* __restrict__ h2)
{
    int tid = threadIdx.x;
    int lane = tid & 63, wid = tid >> 6;
    int pg = lane >> 3, j = lane & 7;
    int p = blockIdx.x * 32 + wid * 8 + pg;       // 16000 pairs
    float u[8][4];
    #pragma unroll
    for (int k = 0; k < 8; ++k)
        #pragma unroll
        for (int q = 0; q < 4; ++q)
            u[k][q] = U2[k * 32 + q * 8 + j];
    float hv = 0.f, cv = 0.f;
    const float* zp = Zx2 + (size_t)p * (16 * 32);
    float* hp = h2 + (size_t)p * (16 * 8);
    for (int t = 0; t < 16; ++t) {
        float zi = zp[t * 32 + j];
        float zf = zp[t * 32 + 8 + j];
        float zg = zp[t * 32 + 16 + j];
        float zo = zp[t * 32 + 24 + j];
        #define LSTM2_STEP(k)                                                        \
        {                                                                            \
            float hk = __int_as_float(__builtin_amdgcn_ds_swizzle(                   \
                __float_as_int(hv), ((k) << 5) | 0x18));                             \
            zi += hk * u[k][0]; zf += hk * u[k][1];                                  \
            zg += hk * u[k][2]; zo += hk * u[k][3];                                  \
        }
        LSTM2_STEP(0) LSTM2_STEP(1) LSTM2_STEP(2) LSTM2_STEP(3)
        LSTM2_STEP(4) LSTM2_STEP(5) LSTM2_STEP(6) LSTM2_STEP(7)
        #undef LSTM2_STEP
        float ig = sigm(zi), fg = sigm(zf), og = sigm(zo);
        cv = fg * cv + ig * tanh_f(zg);
        hv = og * tanh_f(cv);
        hp[t * 8 + j] = hv;
    }
}

template<int NW>
__device__ __forceinline__ void block_reduce2t(float& a, float& b)
{
    #pragma unroll
    for (int off = 32; off; off >>= 1) {
        a += __shfl_xor(a, off);
        b += __shfl_xor(b, off);
    }
    __shared__ float r[2 * NW];
    int tid = threadIdx.x;
    if ((tid & 63) == 0) { r[tid >> 6] = a; r[NW + (tid >> 6)] = b; }
    __syncthreads();
    a = 0.f; b = 0.f;
    #pragma unroll
    for (int w = 0; w < NW; ++w) { a += r[w]; b += r[NW + w]; }
}

// ---------------- LN1 ----------------
__global__ __launch_bounds__(1024) void ln1_kernel(
    const float* __restrict__ h1, const float* __restrict__ g,
    const float* __restrict__ bta, float* __restrict__ o1)
{
    int b = blockIdx.x >> 4, t = blockIdx.x & 15;
    int tid = threadIdx.x;
    float sum = 0.f, sq = 0.f;
    for (int i = tid; i < Nn * H1; i += 1024) {
        int n = i >> 4, j = i & 15;
        float v = h1[(((size_t)b * Nn + n) * Tt + t) * H1 + j];
        sum += v; sq += v * v;
    }
    block_reduce2t<16>(sum, sq);
    float mu = sum * (1.f / (Nn * H1));
    float var = sq * (1.f / (Nn * H1)) - mu * mu;
    float rstd = rsqrtf(var + 1e-5f);
    for (int i = tid; i < Nn * H1; i += 1024) {
        int n = i >> 4, j = i & 15;
        size_t idx = (((size_t)b * Nn + n) * Tt + t) * H1 + j;
        o1[idx] = (h1[idx] - mu) * rstd * g[i] + bta[i];
    }
}

// ---------------- transpose h2 -> enc [B*T][16000] ----------------
__global__ __launch_bounds__(256) void transp_kernel(
    const float* __restrict__ h2, float* __restrict__ enc)
{
    int g = blockIdx.x * 256 + threadIdx.x;   // 2,048,000
    int r = g & 127;
    int p = g >> 7;
    int b = p / Nn, n = p % Nn;
    enc[(size_t)(b * 16 + (r >> 3)) * DMm + n * 8 + (r & 7)] = h2[g];
}

// ---------------- QKV split-K partials: 125 slices of 128 k ----------------
__global__ __launch_bounds__(256) void qkv_part_kernel(
    const float* __restrict__ enc, const float* __restrict__ Wq,
    const float* __restrict__ Wk, const float* __restrict__ Wv,
    float* __restrict__ partial)
{
    __shared__ float encT[128 * 16];          // [kk][r]
    int ks = blockIdx.x, btg = blockIdx.y;    // ks 0..124, btg 0..7
    int tid = threadIdx.x;
    int k0 = ks * 128;
    // stage: coalesced reads (consecutive lanes -> consecutive kk within one row)
    #pragma unroll
    for (int pass = 0; pass < 8; ++pass) {
        int idx = pass * 256 + tid;           // 0..2047
        int r = idx >> 7, kk = idx & 127;
        encT[kk * 16 + r] = enc[(size_t)(btg * 16 + r) * DMm + k0 + kk];
    }
    __syncthreads();
    if (tid >= 192) return;
    int c = tid % 96, rg = tid / 96;          // rg 0/1, 8 rows each
    int cc = c & 31;
    const float* W = (c < 32) ? Wq : ((c < 64) ? Wk : Wv);
    float acc[8] = {};
    #pragma unroll 4
    for (int kk = 0; kk < 128; ++kk) {
        float w = W[(size_t)(k0 + kk) * 32 + cc];
        const float* e = &encT[kk * 16 + rg * 8];
        #pragma unroll
        for (int r8 = 0; r8 < 8; ++r8) acc[r8] += e[r8] * w;
    }
    #pragma unroll
    for (int r8 = 0; r8 < 8; ++r8)
        partial[((size_t)ks * 128 + btg * 16 + rg * 8 + r8) * 96 + c] = acc[r8];
}

// ---------------- QKV reduce (125 partials) ----------------
__global__ __launch_bounds__(256) void qkv_red_kernel(
    const float* __restrict__ partial, float* __restrict__ qb,
    float* __restrict__ kb, float* __restrict__ vb)
{
    int o = blockIdx.x * 256 + threadIdx.x;   // 12288
    int bt = o / 96, c = o % 96;
    float v = 0.f;
    for (int ks = 0; ks < 125; ++ks) v += partial[(size_t)ks * 12288 + o];
    int b = bt >> 4, t = bt & 15;
    int cc = c & 31, h = cc >> 3, dk = cc & 7;
    float* dst = (c < 32) ? qb : ((c < 64) ? kb : vb);
    dst[(((size_t)b * 4 + h) * 16 + t) * 8 + dk] = v;
}

// ---------------- attention ----------------
__global__ __launch_bounds__(256) void attn_kernel(
    const float* __restrict__ qb, const float* __restrict__ kb,
    const float* __restrict__ vb, float* __restrict__ ctx)
{
    int bh = blockIdx.x;
    int b = bh >> 2, h = bh & 3;
    __shared__ float qs[128], ks[128], vs[128], att[16][16];
    int tid = threadIdx.x;
    if (tid < 128) {
        qs[tid] = qb[(size_t)bh * 128 + tid];
        ks[tid] = kb[(size_t)bh * 128 + tid];
        vs[tid] = vb[(size_t)bh * 128 + tid];
    }
    __syncthreads();
    int qt = tid >> 4, kt = tid & 15;
    float s = -1e9f;
    if (kt <= qt) {
        float d = 0.f;
        #pragma unroll
        for (int x = 0; x < 8; ++x) d += qs[qt * 8 + x] * ks[kt * 8 + x];
        s = d * 0.35355339059327373f;
    }
    float mx = s;
    #pragma unroll
    for (int off = 8; off; off >>= 1) mx = fmaxf(mx, __shfl_xor(mx, off, 16));
    float p = __expf(s - mx);
    float sm = p;
    #pragma unroll
    for (int off = 8; off; off >>= 1) sm += __shfl_xor(sm, off, 16);
    att[qt][kt] = p / sm;
    __syncthreads();
    if (tid < 128) {
        int q2 = tid >> 3, dv = tid & 7;
        float cacc = 0.f;
        #pragma unroll
        for (int k2 = 0; k2 < 16; ++k2) cacc += att[q2][k2] * vs[k2 * 8 + dv];
        ctx[((size_t)b * 16 + q2) * 32 + h * 8 + dv] = cacc;
    }
}

// ---------------- ctx @ Wo -> resid2 [BT][16000] ----------------
__global__ __launch_bounds__(256) void ctxwo_kernel(
    const float* __restrict__ ctx, const float* __restrict__ Wo,
    float* __restrict__ resid2)
{
    int bt = blockIdx.y;
    int m = blockIdx.x * 256 + threadIdx.x;
    __shared__ float cs[32];
    if (threadIdx.x < 32) cs[threadIdx.x] = ctx[(size_t)bt * 32 + threadIdx.x];
    __syncthreads();
    if (m < DMm) {
        float acc = 0.f;
        #pragma unroll
        for (int j = 0; j < 32; ++j) acc += cs[j] * Wo[(size_t)j * DMm + m];
        resid2[(size_t)bt * DMm + m] = acc;
    }
}

// ---------------- LN2: writes Xf fp32 [2000][1024] and Xfb bf16 [2048][1024] ----------------
__global__ __launch_bounds__(1024) void ln2_kernel(
    const float* __restrict__ enc, float* __restrict__ resid2,
    const float* __restrict__ g2, const float* __restrict__ b2v,
    float* __restrict__ Xf, bf16* __restrict__ Xfb)
{
    int bt = blockIdx.x;
    int b = bt >> 4, t = bt & 15;
    int tid = threadIdx.x;
    float sum = 0.f, sq = 0.f;
    for (int m = tid; m < DMm; m += 1024) {
        float v = enc[(size_t)bt * DMm + m] + resid2[(size_t)bt * DMm + m];
        resid2[(size_t)bt * DMm + m] = v;
        sum += v; sq += v * v;
    }
    block_reduce2t<16>(sum, sq);
    float mu = sum * (1.f / DMm);
    float var = sq * (1.f / DMm) - mu * mu;
    float rstd = rsqrtf(var + 1e-5f);
    for (int m = tid; m < DMm; m += 1024) {
        float v = resid2[(size_t)bt * DMm + m];
        float y = (v - mu) * rstd * g2[m] + b2v[m];
        int n = m >> 3, j = m & 7;
        size_t o = (size_t)n * 1024 + b * 128 + t * 8 + j;
        Xf[o] = y;
        Xfb[o] = (bf16)y;
    }
}

// ---------------- merged prep: wavelet cvt+pad, theta transpose, activation zero-pad ----------------
__global__ __launch_bounds__(256) void prep_kernel(
    const float* __restrict__ wav, const float* __restrict__ winv,
    bf16* __restrict__ wavb, bf16* __restrict__ winvb,
    const float* __restrict__ th1, const float* __restrict__ th2,
    bf16* __restrict__ th1T, bf16* __restrict__ th2T,
    bf16* __restrict__ X1b, bf16* __restrict__ Gb, bf16* __restrict__ X2b)
{
    int bid = blockIdx.x;
    int tid = threadIdx.x;
    if (bid < 16000) {
        // wavelet fp32 -> bf16, row pad 2000->2016
        const float* src = (bid < 8000) ? wav : winv;
        bf16* dst = (bid < 8000) ? wavb : winvb;
        int row = (bid < 8000) ? bid : bid - 8000;
        if (tid >= 252) return;
        int col = tid * 8;
        bf16 pk[8];
        if (col < 2000) {
            float4 v0 = *(const float4*)(src + (size_t)row * 2000 + col);
            float4 v1 = *(const float4*)(src + (size_t)row * 2000 + col + 4);
            pk[0] = (bf16)v0.x; pk[1] = (bf16)v0.y; pk[2] = (bf16)v0.z; pk[3] = (bf16)v0.w;
            pk[4] = (bf16)v1.x; pk[5] = (bf16)v1.y; pk[6] = (bf16)v1.z; pk[7] = (bf16)v1.w;
        } else {
            #pragma unroll
            for (int i = 0; i < 8; ++i) pk[i] = (bf16)0.f;
        }
        *(uint4*)(dst + (size_t)row * 2016 + col) = *(uint4*)pk;
    } else if (bid < 16064) {
        // theta transpose+cast
        int g = (bid - 16000) * 256 + tid;    // 16384
        int d = g >> 7, d0 = g & 127;
        th1T[g] = (bf16)th1[(size_t)d0 * 128 + d];
        th2T[g] = (bf16)th2[(size_t)d0 * 128 + d];
    } else {
        // zero pad cols [2000,2048) of trans-layout activations: 9216 rows x 48
        int idx = (bid - 16064) * 256 + tid;  // 442,368
        if (idx >= 442368) return;
        int row = idx / 48, col = idx % 48;
        bf16* p;
        if (row < 1024) p = X1b + (size_t)row * 2048;
        else if (row < 5120) p = Gb + (size_t)(row - 1024) * 2048;
        else p = X2b + (size_t)(row - 5120) * 2048;
        p[2000 + col] = (bf16)0.f;
    }
}

// ---------------- theta MFMA ----------------
__global__ __launch_bounds__(256) void theta_mfma(
    const bf16* __restrict__ Act, long sAct, const bf16* __restrict__ thT,
    bf16* __restrict__ Out, long sOut)
{
    __shared__ bf16 As2[128 * 128];
    __shared__ bf16 Bs2[128 * 128];
    const int tid = threadIdx.x;
    const int lane = tid & 63, wave = tid >> 6;
    const int m0 = blockIdx.x * 128, b = blockIdx.y, s = blockIdx.z;
    const bf16* Ab = Act + (size_t)s * sAct + (size_t)m0 * 1024 + b * 128;
    #pragma unroll
    for (int r = 0; r < 8; ++r) {
        int c = r * 256 + wave * 64 + lane;   // 0..2047
        int row = c >> 4, col8 = (c & 15) * 8;
        __builtin_amdgcn_global_load_lds(
            (const GAS unsigned int*)(Ab + (size_t)row * 1024 + col8),
            (LAS unsigned int*)(As2 + c * 8), 16, 0, 0);
        __builtin_amdgcn_global_load_lds(
            (const GAS unsigned int*)(thT + (size_t)row * 128 + col8),
            (LAS unsigned int*)(Bs2 + c * 8), 16, 0, 0);
    }
    __syncthreads();
    const int wr = wave >> 1, wc = wave & 1;
    const int fm = lane & 15, quad = lane >> 4;
    f32x4 acc[4][4] = {};
    #pragma unroll
    for (int ks = 0; ks < 4; ++ks) {
        bf16x8 af[4], bfv[4];
        #pragma unroll
        for (int i = 0; i < 4; ++i)
            af[i] = *(const bf16x8*)(As2 + (wr * 64 + i * 16 + fm) * 128 + ks * 32 + quad * 8);
        #pragma unroll
        for (int j = 0; j < 4; ++j)
            bfv[j] = *(const bf16x8*)(Bs2 + (wc * 64 + j * 16 + fm) * 128 + ks * 32 + quad * 8);
        #pragma unroll
        for (int i = 0; i < 4; ++i)
            #pragma unroll
            for (int j = 0; j < 4; ++j)
                acc[i][j] = __builtin_amdgcn_mfma_f32_16x16x32_bf16(
                    af[i], bfv[j], acc[i][j], 0, 0, 0);
    }
    const int fm4 = quad * 4;
    #pragma unroll
    for (int i = 0; i < 4; ++i) {
        int m = m0 + wr * 64 + i * 16 + fm4;
        if (m >= 2000) continue;
        #pragma unroll
        for (int j = 0; j < 4; ++j) {
            int d = wc * 64 + j * 16 + fm;
            f32x4 v = acc[i][j];
            bf16 pk[4] = {(bf16)v[0], (bf16)v[1], (bf16)v[2], (bf16)v[3]};
            *(uint2*)(Out + (size_t)s * sOut + (size_t)(b * 128 + d) * 2048 + m) = *(uint2*)pk;
        }
    }
}

// ---------------- bf16 MFMA GEMM ----------------
__global__ __launch_bounds__(256) void hgemm_bf16(
    const bf16* __restrict__ A, long sA,
    const bf16* __restrict__ Bt, long sB,
    bf16* __restrict__ C, long sC,
    const float* __restrict__ rowscale, int mode)
{
    __shared__ bf16 As[128 * 32];
    __shared__ bf16 Bs[128 * 32];
    const int tid = threadIdx.x;
    const int lane = tid & 63, wave = tid >> 6;
    const int m0 = blockIdx.x * 128, n0 = blockIdx.y * 128;
    const int s = blockIdx.z;
    const bf16* Abase = A + (size_t)s * sA;
    const bf16* Bbase = Bt + (size_t)s * sB;
    const int wr = wave >> 1, wc = wave & 1;
    const int fm = lane & 15, quad = lane >> 4;

    const int c0 = wave * 128 + lane, c1 = c0 + 64;
    int rA0 = m0 + (c0 >> 2); if (rA0 > 1999) rA0 = 1999;
    int rA1 = m0 + (c1 >> 2); if (rA1 > 1999) rA1 = 1999;
    const bf16* a0p = Abase + (size_t)rA0 * 2016 + (c0 & 3) * 8;
    const bf16* a1p = Abase + (size_t)rA1 * 2016 + (c1 & 3) * 8;
    const bf16* b0p = Bbase + (size_t)(n0 + (c0 >> 2)) * 2048 + (c0 & 3) * 8;
    const bf16* b1p = Bbase + (size_t)(n0 + (c1 >> 2)) * 2048 + (c1 & 3) * 8;
    bf16* as0 = As + c0 * 8; bf16* as1 = As + c1 * 8;
    bf16* bs0 = Bs + c0 * 8; bf16* bs1 = Bs + c1 * 8;

    f32x4 acc[4][4] = {};
    for (int kt = 0; kt < 63; ++kt) {
        const int k0 = kt * 32;
        __builtin_amdgcn_global_load_lds((const GAS unsigned int*)(a0p + k0),
                                         (LAS unsigned int*)as0, 16, 0, 0);
        __builtin_amdgcn_global_load_lds((const GAS unsigned int*)(a1p + k0),
                                         (LAS unsigned int*)as1, 16, 0, 0);
        __builtin_amdgcn_global_load_lds((const GAS unsigned int*)(b0p + k0),
                                         (LAS unsigned int*)bs0, 16, 0, 0);
        __builtin_amdgcn_global_load_lds((const GAS unsigned int*)(b1p + k0),
                                         (LAS unsigned int*)bs1, 16, 0, 0);
        __syncthreads();
        bf16x8 af[4], bfv[4];
        #pragma unroll
        for (int i = 0; i < 4; ++i)
            af[i] = *(const bf16x8*)(As + (wr * 64 + i * 16 + fm) * 32 + quad * 8);
        #pragma unroll
        for (int j = 0; j < 4; ++j)
            bfv[j] = *(const bf16x8*)(Bs + (wc * 64 + j * 16 + fm) * 32 + quad * 8);
        #pragma unroll
        for (int i = 0; i < 4; ++i)
            #pragma unroll
            for (int j = 0; j < 4; ++j)
                acc[i][j] = __builtin_amdgcn_mfma_f32_16x16x32_bf16(
                    af[i], bfv[j], acc[i][j], 0, 0, 0);
        __syncthreads();
    }

    const int fm4 = quad * 4;
    if (mode == 0) {
        #pragma unroll
        for (int i = 0; i < 4; ++i) {
            int m = m0 + wr * 64 + i * 16 + fm4;
            if (m >= 2000) continue;
            #pragma unroll
            for (int j = 0; j < 4; ++j) {
                int n = n0 + wc * 64 + j * 16 + fm;
                f32x4 v = acc[i][j];
                float4 rs = *(const float4*)(rowscale + m);
                v[0] *= rs.x; v[1] *= rs.y; v[2] *= rs.z; v[3] *= rs.w;
                bf16 pk[4] = {(bf16)v[0], (bf16)v[1], (bf16)v[2], (bf16)v[3]};
                *(uint2*)(C + (size_t)s * sC + (size_t)n * 2048 + m) = *(uint2*)pk;
            }
        }
    } else {
        #pragma unroll
        for (int i = 0; i < 4; ++i) {
            int mb_ = m0 + wr * 64 + i * 16 + fm4;
            #pragma unroll
            for (int j = 0; j < 4; ++j) {
                int n = n0 + wc * 64 + j * 16 + fm;
                #pragma unroll
                for (int r = 0; r < 4; ++r) {
                    int m = mb_ + r;
                    if (m < 2000) {
                        float x = acc[i][j][r];
                        x = x > 0.f ? x : 0.1f * x;
                        C[(size_t)s * sC + (size_t)m * 1024 + n] = (bf16)x;
                    }
                }
            }
        }
    }
}

// ---------------- final MLP (fuses par-weighted sum over s) ----------------
__global__ __launch_bounds__(256) void mlp_kernel(
    const float* __restrict__ Xf, const bf16* __restrict__ F2,
    const float* __restrict__ par, const float* __restrict__ W1m,
    const float* __restrict__ b1m, const float* __restrict__ W2m,
    const float* __restrict__ b2m, float* __restrict__ out)
{
    __shared__ float w1s[256], b1s[16], w2s[16];
    int tid = threadIdx.x;
    w1s[tid] = W1m[tid];
    if (tid < 16) { b1s[tid] = b1m[tid]; w2s[tid] = W2m[tid]; }
    __syncthreads();
    int g = blockIdx.x * 256 + tid;           // 256000
    int t = g & 15;
    int r = g >> 4;
    int b = r / Nn, n = r % Nn;
    size_t base = (size_t)n * 1024 + b * 128 + t * 8;
    float p0 = par[0], p1 = par[1], p2 = par[2], p3 = par[3];
    float c[16];
    #pragma unroll
    for (int j = 0; j < 8; ++j) {
        c[j] = Xf[base + j];
        c[8 + j] = p0 * (float)F2[base + j]
                 + p1 * (float)F2[2097152 + base + j]
                 + p2 * (float)F2[4194304 + base + j]
                 + p3 * (float)F2[6291456 + base + j];
    }
    float acc = b2m[0];
    #pragma unroll
    for (int hh = 0; hh < 16; ++hh) {
        float hs = b1s[hh];
        #pragma unroll
        for (int cc = 0; cc < 16; ++cc) hs += c[cc] * w1s[cc * 16 + hh];
        acc += fmaxf(hs, 0.f) * w2s[hh];
    }
    out[g] = acc;
}

extern "C" void kernel_launch(void* const* d_in, const int* in_sizes, int n_in,
                              void* d_out, int out_size, void* d_ws, size_t ws_size,
                              hipStream_t stream)
{
    const float* inputs = (const float*)d_in[0];
    const float* emb_W  = (const float*)d_in[1];
    const float* emb_b  = (const float*)d_in[2];
    const float* W1     = (const float*)d_in[3];
    const float* U1     = (const float*)d_in[4];
    const float* b1     = (const float*)d_in[5];
    const float* ln1_g  = (const float*)d_in[6];
    const float* ln1_b  = (const float*)d_in[7];
    const float* W2     = (const float*)d_in[8];
    const float* U2     = (const float*)d_in[9];
    const float* b2     = (const float*)d_in[10];
    const float* Wq     = (const float*)d_in[11];
    const float* Wk     = (const float*)d_in[12];
    const float* Wv     = (const float*)d_in[13];
    const float* Wo     = (const float*)d_in[14];
    const float* ln2_g  = (const float*)d_in[15];
    const float* ln2_b  = (const float*)d_in[16];
    const float* par    = (const float*)d_in[17];
    const float* theta1 = (const float*)d_in[18];
    const float* diag1  = (const float*)d_in[19];
    const float* theta2 = (const float*)d_in[20];
    const float* diag2  = (const float*)d_in[21];
    const float* mlp1_W = (const float*)d_in[22];
    const float* mlp1_b = (const float*)d_in[23];
    const float* mlp2_W = (const float*)d_in[24];
    const float* mlp2_b = (const float*)d_in[25];
    const float* wav    = (const float*)d_in[26];
    const float* winv   = (const float*)d_in[27];
    float* ws  = (float*)d_ws;
    float* out = (float*)d_out;

    // ---- workspace layout (float offsets) ----
    float* Zx1    = ws + 0;          // dead after lstm1
    float* h1     = ws + 16384000;   // dead after ln1
    float* o1     = ws + 0;          // dead after zx2
    float* Zx2    = ws + 4096000;    // dead after lstm2
    float* h2     = ws + 12288000;   // dead after transp
    float* enc    = ws + 10240000;   // dead after ln2
    float* qpart  = ws + 12288000;   // [125][128][96] = 1,536,000 (h2 dead)
    float* qb     = ws + 13824000;
    float* kb     = ws + 13828096;
    float* vb     = ws + 13832192;
    float* ctx    = ws + 13836288;
    float* resid2 = ws + 4096000;    // written at ctxwo (Zx2 dead)
    float* Xf     = ws + 16128000;   // fp32 [2000][1024], live to end (h1 dead)
    bf16*  Xfb    = (bf16*)(ws + 18176000);  // [2048][1024] node-major bf16
    bf16*  wavb   = (bf16*)(ws + 0);         // [4][2000][2016] (after ln2)
    bf16*  winvb  = (bf16*)(ws + 8064000);
    bf16*  X1b    = (bf16*)(ws + 19224576);  // [1024][2048] trans
    bf16*  Gb     = (bf16*)(ws + 20273152);  // [4][1024][2048] trans
    bf16*  Fb     = (bf16*)(ws + 24467456);  // [4][2048][1024] node-major
    bf16*  X2b    = (bf16*)(ws + 28661760);  // [4][1024][2048] trans
    bf16*  F2b    = (bf16*)(ws + 24467456);  // aliases Fb
    bf16*  th1T   = (bf16*)(ws + 32856064);  // [128][128]
    bf16*  th2T   = (bf16*)(ws + 32864256);  // [128][128]
    float* Wf     = ws + 20480000;   // fused embed*W1 (inside Gb region, dead before Gb)
    float* bfB    = ws + 20480640;

    // ---- stage A ----
    wf_kernel<<<1, 704, 0, stream>>>(emb_W, emb_b, W1, b1, Wf, bfB);
    zx1_kernel<<<64000, 256, 0, stream>>>(inputs, Wf, bfB, Zx1);
    lstm1_kernel<<<1000, 256, 0, stream>>>(Zx1, U1, h1);
    ln1_kernel<<<128, 1024, 0, stream>>>(h1, ln1_g, ln1_b, o1);
    zx2_kernel<<<32000, 256, 0, stream>>>(o1, W2, b2, Zx2);
    lstm2_kernel<<<500, 256, 0, stream>>>(Zx2, U2, h2);
    transp_kernel<<<8000, 256, 0, stream>>>(h2, enc);
    qkv_part_kernel<<<dim3(125, 8), 256, 0, stream>>>(enc, Wq, Wk, Wv, qpart);
    qkv_red_kernel<<<48, 256, 0, stream>>>(qpart, qb, kb, vb);
    attn_kernel<<<32, 256, 0, stream>>>(qb, kb, vb, ctx);
    ctxwo_kernel<<<dim3(63, 128), 256, 0, stream>>>(ctx, Wo, resid2);
    ln2_kernel<<<128, 1024, 0, stream>>>(enc, resid2, ln2_g, ln2_b, Xf, Xfb);

    // ---- stage B: merged conversions + padding ----
    prep_kernel<<<17792, 256, 0, stream>>>(wav, winv, wavb, winvb,
                                           theta1, theta2, th1T, th2T,
                                           X1b, Gb, X2b);

    // ---- hypergraph wavelet block ----
    const long sW = 4032000;     // wavelet slab stride (bf16)
    const long sAct = 2097152;   // [1024][2048] / [2048][1024] bf16
    theta_mfma<<<dim3(16, 8, 1), 256, 0, stream>>>(Xfb, 0, th1T, X1b, 0);
    hgemm_bf16<<<dim3(16, 8, 4), 256, 0, stream>>>(winvb, sW, X1b, 0, Gb, sAct, diag1, 0);
    hgemm_bf16<<<dim3(16, 8, 4), 256, 0, stream>>>(wavb, sW, Gb, sAct, Fb, sAct, nullptr, 1);
    theta_mfma<<<dim3(16, 8, 4), 256, 0, stream>>>(Fb, sAct, th2T, X2b, sAct);
    hgemm_bf16<<<dim3(16, 8, 4), 256, 0, stream>>>(winvb, sW, X2b, sAct, Gb, sAct, diag2, 0);
    hgemm_bf16<<<dim3(16, 8, 4), 256, 0, stream>>>(wavb, sW, Gb, sAct, F2b, sAct, nullptr, 1);

    // ---- head ----
    mlp_kernel<<<1000, 256, 0, stream>>>(Xf, F2b, par, mlp1_W, mlp1_b,
                                         mlp2_W, mlp2_b, out);
}